// Round 7
// baseline (336.544 us; speedup 1.0000x reference)
//
#include <hip/hip_runtime.h>
#include <hip/hip_fp16.h>
#include <math.h>

// ---------------- problem constants ----------------
constexpr int NN   = 50000;          // nodes
constexpr int NE   = 150000;         // edges
constexpr int DIN  = 48;
constexpr int DH   = 64;
constexpr int DE   = 16;
constexpr int NHD  = 10;             // heads
constexpr int NL   = 3;              // layers
constexpr int DOUTC= 128;
constexpr int NG   = 4096;           // graphs
constexpr int E2   = NE + NN;        // edges incl self loops (200000)
constexpr int SCAN_B  = 256;
constexpr int SCAN_NB = (NN + SCAN_B - 1) / SCAN_B;   // 196

typedef __bf16 v8bf __attribute__((ext_vector_type(8)));
typedef short  v8s  __attribute__((ext_vector_type(8)));
typedef float  v4f  __attribute__((ext_vector_type(4)));

__device__ inline unsigned short f2bf(float f) {
    unsigned u = __builtin_bit_cast(unsigned, f);
    unsigned r = (u + 0x7FFFu + ((u >> 16) & 1u)) >> 16;
    return (unsigned short)r;
}

__device__ inline v4f MF(v8s a, v8s b, v4f c) {
    return __builtin_amdgcn_mfma_f32_16x16x32_bf16(
        __builtin_bit_cast(v8bf, a), __builtin_bit_cast(v8bf, b), c, 0, 0, 0);
}
__device__ inline v4f MFB(v8bf a, v8s b, v4f c) {
    return __builtin_amdgcn_mfma_f32_16x16x32_bf16(
        a, __builtin_bit_cast(v8bf, b), c, 0, 0, 0);
}

// broadcast a float/int from a compile-time lane (no LDS)
#define RLF(v, l) __builtin_bit_cast(float, __builtin_amdgcn_readlane(__builtin_bit_cast(int, (v)), (l)))
#define RLI(v, l) __builtin_amdgcn_readlane((v), (l))

// ---------------- preprocessing ----------------
__global__ void k_cnt(const int* __restrict__ dst, int* __restrict__ cnt) {
    int e = blockIdx.x * blockDim.x + threadIdx.x;
    if (e < NE) atomicAdd(&cnt[dst[e]], 1);
}

__global__ void k_scan_a(const int* __restrict__ cnt, int* __restrict__ bsum) {
    __shared__ int s[SCAN_B];
    int i = blockIdx.x * SCAN_B + threadIdx.x;
    s[threadIdx.x] = (i < NN) ? (cnt[i] + 1) : 0;   // +1 = self loop
    __syncthreads();
    for (int off = SCAN_B / 2; off > 0; off >>= 1) {
        if (threadIdx.x < off) s[threadIdx.x] += s[threadIdx.x + off];
        __syncthreads();
    }
    if (threadIdx.x == 0) bsum[blockIdx.x] = s[0];
}

__global__ void k_scan_b(int* __restrict__ bsum) {
    if (threadIdx.x == 0 && blockIdx.x == 0) {
        int acc = 0;
        for (int i = 0; i < SCAN_NB; ++i) { int v = bsum[i]; bsum[i] = acc; acc += v; }
    }
}

__global__ void k_scan_c(const int* __restrict__ cnt, const int* __restrict__ bsum,
                         int* __restrict__ rp) {
    __shared__ int s[SCAN_B];
    int i = blockIdx.x * SCAN_B + threadIdx.x;
    int v = (i < NN) ? (cnt[i] + 1) : 0;
    s[threadIdx.x] = v;
    __syncthreads();
    for (int off = 1; off < SCAN_B; off <<= 1) {
        int t = (threadIdx.x >= off) ? s[threadIdx.x - off] : 0;
        __syncthreads();
        s[threadIdx.x] += t;
        __syncthreads();
    }
    if (i < NN) {
        int excl = bsum[blockIdx.x] + s[threadIdx.x] - v;
        rp[i] = excl;
        if (i == NN - 1) rp[NN] = excl + v;
    }
}

__global__ void k_csr_fill(const int* __restrict__ src, const int* __restrict__ dst,
                           const int* __restrict__ rp, int* __restrict__ cursor,
                           int* __restrict__ eidx, int* __restrict__ scsr,
                           int* __restrict__ dcsr) {
    int e = blockIdx.x * blockDim.x + threadIdx.x;
    if (e >= E2) return;
    int d  = (e < NE) ? dst[e] : (e - NE);
    int sn = (e < NE) ? src[e] : d;
    int pos = atomicAdd(&cursor[d], 1);
    int s = rp[d] + pos;
    eidx[s] = e; scsr[s] = sn; dcsr[s] = d;
}

// self-loop attr = mean of real incoming edge attrs (no atomics, via CSR)
__global__ void k_loopattr(const int* __restrict__ rp, const int* __restrict__ eidx,
                           const int* __restrict__ cnt, const float* __restrict__ ea,
                           float* __restrict__ loop) {
    int tid = blockIdx.x * blockDim.x + threadIdx.x;
    if (tid >= NN * DE) return;
    int n = tid >> 4, d = tid & 15;
    int r0 = rp[n], r1 = rp[n + 1];
    float s = 0.f;
    for (int t = r0; t < r1; ++t) {
        int eid = eidx[t];
        if (eid < NE) s += ea[(size_t)eid * DE + d];
    }
    int c = cnt[n];
    loop[tid] = s * ((c > 1) ? (1.0f / (float)c) : 1.0f);
}

// graph row pointers from sorted batch ids
__global__ void k_grp(const int* __restrict__ batch, int* __restrict__ grp) {
    int n = blockIdx.x * blockDim.x + threadIdx.x;
    if (n >= NN) return;
    int b = batch[n];
    int pb = (n == 0) ? -1 : batch[n - 1];
    for (int g = pb + 1; g <= b; ++g) grp[g] = n;
    if (n == NN - 1) for (int g = b + 1; g <= NG; ++g) grp[g] = NN;
}

// ---------------- W_emb hi/lo bf16 in B-frag layout: BH/BL[c*64+k] ----------------
__global__ void k_prepWemb(const float* __restrict__ W, unsigned short* __restrict__ BH,
                           unsigned short* __restrict__ BL) {
    int tid = blockIdx.x * blockDim.x + threadIdx.x;
    if (tid >= DH * 64) return;
    int c = tid >> 6, k = tid & 63;
    float v = (k < DIN) ? W[(size_t)k * DH + c] : 0.f;
    __bf16 hi = (__bf16)v;
    BH[tid] = __builtin_bit_cast(unsigned short, hi);
    BL[tid] = __builtin_bit_cast(unsigned short, (__bf16)(v - (float)hi));
}

// ---------------- embedding via MFMA (hi/lo split) + fused layer-0 scores ----------------
// 256 threads = 4 waves; 64 nodes/block; wave w owns row-tile w (16 nodes).
__global__ __launch_bounds__(256) void k_emb(const float* __restrict__ x,
        const unsigned short* __restrict__ BH, const unsigned short* __restrict__ BL,
        const float* __restrict__ bemb, const unsigned short* __restrict__ WcB,
        float* __restrict__ h, float* __restrict__ S) {
    __shared__ __align__(16) unsigned short hlb[4][16 * 72];
    const int tid = threadIdx.x;
    const int w = tid >> 6, lane = tid & 63;
    const int la = lane & 15, lb = lane >> 4;
    const int rowbase = blockIdx.x * 64 + w * 16;
    const int nA = rowbase + la;

    v8bf ah[2], al[2];
#pragma unroll
    for (int ks = 0; ks < 2; ++ks) {
        const int k0 = ks * 32 + lb * 8;
        float xv[8];
        if (nA < NN && k0 < DIN) {
            const float* xp = x + (size_t)nA * DIN + k0;
            float4 v0 = *(const float4*)xp;
            float4 v1 = *(const float4*)(xp + 4);
            xv[0]=v0.x; xv[1]=v0.y; xv[2]=v0.z; xv[3]=v0.w;
            xv[4]=v1.x; xv[5]=v1.y; xv[6]=v1.z; xv[7]=v1.w;
        } else {
#pragma unroll
            for (int e = 0; e < 8; ++e) xv[e] = 0.f;
        }
#pragma unroll
        for (int e = 0; e < 8; ++e) {
            __bf16 hi = (__bf16)xv[e];
            ah[ks][e] = hi;
            al[ks][e] = (__bf16)(xv[e] - (float)hi);
        }
    }
    v4f acc[4];
#pragma unroll
    for (int ct = 0; ct < 4; ++ct) acc[ct] = (v4f){0.f, 0.f, 0.f, 0.f};
#pragma unroll
    for (int ct = 0; ct < 4; ++ct) {
#pragma unroll
        for (int ks = 0; ks < 2; ++ks) {
            const int boff = (ct * 16 + la) * 64 + ks * 32 + lb * 8;
            v8s bh = *(const v8s*)&BH[boff];
            v8s bl = *(const v8s*)&BL[boff];
            acc[ct] = MFB(ah[ks], bh, acc[ct]);
            acc[ct] = MFB(al[ks], bh, acc[ct]);
            acc[ct] = MFB(ah[ks], bl, acc[ct]);
        }
    }
    // epilogue: + b_emb, write h, stash bf16 tile
#pragma unroll
    for (int ct = 0; ct < 4; ++ct) {
        const int c = ct * 16 + la;
        const float bi = bemb[c];
#pragma unroll
        for (int r = 0; r < 4; ++r) {
            const int row = lb * 4 + r;
            const int n = rowbase + row;
            float v = acc[ct][r] + bi;
            if (n < NN) h[(size_t)n * DH + c] = v;
            hlb[w][row * 72 + c] = f2bf(v);
        }
    }
    __syncthreads();
    // layer-0 scores: S[16 rows][20] per wave via 2 col-tiles
    v4f s0 = {0.f,0.f,0.f,0.f}, s1 = {0.f,0.f,0.f,0.f};
#pragma unroll
    for (int t = 0; t < 2; ++t) {
        v8s av = *(const v8s*)&hlb[w][la * 72 + t * 32 + lb * 8];
        v8s b0 = *(const v8s*)&WcB[(size_t)(lane) * 16 + t * 8];
        v8s b1 = *(const v8s*)&WcB[(size_t)(64 + lane) * 16 + t * 8];
        s0 = MF(av, b0, s0);
        s1 = MF(av, b1, s1);
    }
#pragma unroll
    for (int r = 0; r < 4; ++r) {
        const int n = rowbase + lb * 4 + r;
        if (n < NN) {
            S[(size_t)n * 20 + la] = s0[r];
            if (la < 4) S[(size_t)n * 20 + 16 + la] = s1[r];
        }
    }
}

// ---------------- all-layer combined attention weights (+ transposed WeT) ----------------
__global__ void k_comb3(const float* __restrict__ Ws, const float* __restrict__ asrc,
                        const float* __restrict__ adst, const float* __restrict__ We_in,
                        const float* __restrict__ aedge, float* __restrict__ Wcomb,
                        float* __restrict__ WeT) {
    int layer = blockIdx.y;
    int tid = blockIdx.x * blockDim.x + threadIdx.x;
    if (tid < DH * 2 * NHD) {                      // 1280
        int k = tid / 20, j = tid % 20;
        int hh = j % NHD;
        const float* a = ((j < NHD) ? asrc : adst) + (size_t)layer * NHD * DH + hh * DH;
        const float* w = Ws + ((size_t)layer * DH + k) * (NHD * DH) + hh * DH;
        float s = 0.f;
#pragma unroll
        for (int f = 0; f < DH; ++f) s += w[f] * a[f];
        Wcomb[layer * 1280 + tid] = s;
    } else if (tid < DH * 2 * NHD + DE * NHD) {    // +160
        int t = tid - DH * 2 * NHD;
        int d = t / NHD, hh = t % NHD;
        const float* a = aedge + (size_t)layer * NHD * DH + hh * DH;
        const float* w = We_in + ((size_t)layer * DE + d) * (NHD * DH) + hh * DH;
        float s = 0.f;
#pragma unroll
        for (int f = 0; f < DH; ++f) s += w[f] * a[f];
        WeT[layer * 160 + hh * 16 + d] = s;        // [h][d] transposed
    }
}

// ---------------- Bt[l][f][j'] with j' = k*10+q : B[j'][f] = Ws[l][k][q*64+f]*0.1, bf16 ----------------
__global__ void k_prepB3(const float* __restrict__ Ws, unsigned short* __restrict__ Bt) {
    int layer = blockIdx.y;
    int tid = blockIdx.x * blockDim.x + threadIdx.x;
    if (tid >= DH * 640) return;
    int f = tid / 640, jp = tid % 640;
    int k = jp / 10, q = jp % 10;
    float v = Ws[(size_t)layer * DH * 640 + (size_t)k * 640 + q * 64 + f] * 0.1f;
    Bt[(size_t)layer * DH * 640 + tid] = f2bf(v);
}

// ---------------- Wcomb in MFMA B-fragment layout (bf16), per layer, 2 col-tiles ----------------
__global__ void k_wcb(const float* __restrict__ Wcomb, unsigned short* __restrict__ WcB) {
    int tid = blockIdx.x * blockDim.x + threadIdx.x;
    if (tid >= NL * 2 * 64 * 16) return;
    int l = tid / 2048, r = tid % 2048;
    int tile = r / 1024, rr = r % 1024;
    int ln = rr / 16, idx = rr % 16;
    int t = idx / 8, e = idx % 8;
    int k = t * 32 + (ln >> 4) * 8 + e;
    int jc = ln & 15;
    float v = 0.f;
    if (tile == 0 || jc < 4) v = Wcomb[l * 1280 + k * 20 + tile * 16 + jc];
    WcB[tid] = f2bf(v);
}

// ---------------- alpha per (slot, head): fully parallel, a_e inline, fp16 out ----------------
__global__ void k_alpha(const float* __restrict__ S, const float* __restrict__ ea,
                        const float* __restrict__ loop, const float* __restrict__ WeT,
                        const int* __restrict__ scsr, const int* __restrict__ dcsr,
                        const int* __restrict__ eidx, __half* __restrict__ wraw) {
    int tid = blockIdx.x * blockDim.x + threadIdx.x;
    if (tid >= E2 * NHD) return;
    int s = tid / NHD, h = tid - (tid / NHD) * NHD;
    int sn = scsr[s], dn = dcsr[s], eid = eidx[s];
    const float* ar = (eid < NE) ? (ea + (size_t)eid * DE) : (loop + (size_t)(eid - NE) * DE);
    const float* wt = WeT + h * 16;
    float4 a0 = *(const float4*)(ar + 0);
    float4 a1 = *(const float4*)(ar + 4);
    float4 a2 = *(const float4*)(ar + 8);
    float4 a3 = *(const float4*)(ar + 12);
    float4 w0 = *(const float4*)(wt + 0);
    float4 w1 = *(const float4*)(wt + 4);
    float4 w2 = *(const float4*)(wt + 8);
    float4 w3 = *(const float4*)(wt + 12);
    float aev = a0.x*w0.x + a0.y*w0.y + a0.z*w0.z + a0.w*w0.w
              + a1.x*w1.x + a1.y*w1.y + a1.z*w1.z + a1.w*w1.w
              + a2.x*w2.x + a2.y*w2.y + a2.z*w2.z + a2.w*w2.w
              + a3.x*w3.x + a3.y*w3.y + a3.z*w3.z + a3.w*w3.w;
    float a = S[(size_t)sn * 20 + h] + S[(size_t)dn * 20 + 10 + h] + aev;
    a = (a > 0.f) ? a : 0.2f * a;
    wraw[tid] = (__half)a;
}

// ---------------- per-(node,head): streaming max + 1/z over fp16 alphas ----------------
__global__ void k_mz2(const __half* __restrict__ wraw, const int* __restrict__ rp,
                      float2* __restrict__ mz2) {
    int tid = blockIdx.x * blockDim.x + threadIdx.x;
    if (tid >= NN * NHD) return;
    int n = tid / NHD, h = tid - (tid / NHD) * NHD;
    int r0 = rp[n], r1 = rp[n + 1];
    float m = -1e30f;
    for (int s = r0; s < r1; ++s) m = fmaxf(m, (float)wraw[(size_t)s * NHD + h]);
    float z = 0.f;
    for (int s = r0; s < r1; ++s) z += __expf((float)wraw[(size_t)s * NHD + h] - m);
    mz2[tid] = make_float2(m, 1.f / z);
}

// ---------------- fused layer: reg-only agg -> LDS G tile -> MFMA -> epilogue -> next-S ----------------
// 512 threads = 8 waves, 32 nodes/block; wave w owns nodes w*4..w*4+3 in Phase A.
__global__ __launch_bounds__(512) void k_layer(
        const __half* __restrict__ wraw, const float2* __restrict__ mz2,
        const float* __restrict__ hin, const int* __restrict__ rp,
        const int* __restrict__ scsr, const unsigned short* __restrict__ Bt,
        const unsigned short* __restrict__ WcB, int do_s, float* __restrict__ Sout,
        const float* __restrict__ bias, const float* __restrict__ gam,
        const float* __restrict__ bet, const float* __restrict__ mean,
        const float* __restrict__ var, float* __restrict__ hout) {
    __shared__ __align__(16) unsigned short Gl[32 * 648];   // 41472 B

    const int tid = threadIdx.x;
    const int w = tid >> 6, lane = tid & 63;
    const int el = lane / NHD, hh = lane - el * NHD;  // valid for lane<60
    const int blk = blockIdx.x;
    const int nb4 = blk * 32 + w * 4;

    // ---- Phase A: stage softmax weights + src for 4 nodes ----
    int r0a[4], dga[4]; float wreg[4]; int sreg[4];
#pragma unroll
    for (int i = 0; i < 4; ++i) {
        const int n = nb4 + i;
        int r0 = 0, dg = 0;
        if (n < NN) { r0 = rp[n]; dg = rp[n + 1] - r0; }
        r0a[i] = r0; dga[i] = dg;
        float wv = 0.f;
        if (lane < 60 && el < dg) {
            float a = (float)wraw[(size_t)r0 * NHD + lane];
            float2 mz = mz2[(size_t)n * NHD + hh];
            wv = __expf(a - mz.x) * mz.y;
        }
        wreg[i] = wv;
        sreg[i] = (lane < 6 && lane < dg) ? scsr[r0 + lane] : 0;
    }
    float hv[4][6];
#pragma unroll
    for (int i = 0; i < 4; ++i) {
#pragma unroll
        for (int j = 0; j < 6; ++j) {
            int sv = RLI(sreg[i], j);
            hv[i][j] = hin[(size_t)sv * DH + lane];
        }
    }
#pragma unroll
    for (int i = 0; i < 4; ++i) {
        float g[NHD];
#pragma unroll
        for (int q = 0; q < NHD; ++q) g[q] = 0.f;
#pragma unroll
        for (int j = 0; j < 6; ++j) {
#pragma unroll
            for (int q = 0; q < NHD; ++q)
                g[q] = fmaf(RLF(wreg[i], j * 10 + q), hv[i][j], g[q]);
        }
        // tail chunks (deg > 6)
        const int n = nb4 + i;
        for (int c0 = 6; c0 < dga[i]; c0 += 6) {
            float w2 = (lane < 60 && el < dga[i] - c0)
                       ? __expf((float)wraw[(size_t)(r0a[i] + c0) * NHD + lane]
                                - mz2[(size_t)n * NHD + hh].x) * mz2[(size_t)n * NHD + hh].y
                       : 0.f;
            int s2 = (lane < 6 && c0 + lane < dga[i]) ? scsr[r0a[i] + c0 + lane] : 0;
            float hv2[6];
#pragma unroll
            for (int j = 0; j < 6; ++j) {
                int sv = RLI(s2, j);
                hv2[j] = hin[(size_t)sv * DH + lane];
            }
#pragma unroll
            for (int j = 0; j < 6; ++j)
#pragma unroll
                for (int q = 0; q < NHD; ++q)
                    g[q] = fmaf(RLF(w2, j * 10 + q), hv2[j], g[q]);
        }
        // write G row: G[li][k*10+q], lane=k holds 10 consecutive bf16 -> 5 packed b32
        const int li = w * 4 + i;
        const int base = li * 648 + lane * 10;
#pragma unroll
        for (int p = 0; p < 5; ++p) {
            unsigned u = (unsigned)f2bf(g[2 * p]) | ((unsigned)f2bf(g[2 * p + 1]) << 16);
            *(unsigned*)&Gl[base + 2 * p] = u;
        }
    }
    __syncthreads();

    // ---- Phase B: xc = G @ B, 8 tiles (2 row x 4 col) across 8 waves ----
    const int rt = w & 1, ct = w >> 1;
    const int la = lane & 15, lb = lane >> 4;
    v4f acc = {0.f, 0.f, 0.f, 0.f};
    const size_t brow = (size_t)(ct * 16 + la) * 640;
#pragma unroll 5
    for (int t = 0; t < 20; ++t) {
        const int koff = t * 32 + lb * 8;
        v8s av = *(const v8s*)&Gl[(rt * 16 + la) * 648 + koff];
        v8s bv = *(const v8s*)&Bt[brow + koff];
        acc = MF(av, bv, acc);
    }
    __syncthreads();      // all Gl reads done; epilogue reuses Gl as bf16 h-tile

    // ---- epilogue: bias + BN + gelu + residual; stash hout tile (bf16) in LDS ----
    unsigned short* hlb = Gl;           // [32][72] bf16 (alias)
    const int f = ct * 16 + la;
    const float bi = bias[f], gm = gam[f], bt_ = bet[f], mu = mean[f];
    const float iv = rsqrtf(var[f] + 1e-5f);
#pragma unroll
    for (int r = 0; r < 4; ++r) {
        const int local = rt * 16 + lb * 4 + r;
        const int n = blk * 32 + local;
        float v = acc[r] + bi;
        v = (v - mu) * gm * iv + bt_;
        v = 0.5f * v * (1.0f + erff(v * 0.70710678118654752f));
        float hnew = v;
        if (n < NN) {
            hnew += hin[(size_t)n * DH + f];
            hout[(size_t)n * DH + f] = hnew;
        }
        hlb[local * 72 + f] = f2bf(hnew);
    }

    // ---- fused next-layer scores ----
    if (do_s) {
        __syncthreads();
        if (w < 4) {
            const int rt2 = w >> 1, cts = w & 1;
            v4f sa = {0.f, 0.f, 0.f, 0.f};
#pragma unroll
            for (int t = 0; t < 2; ++t) {
                v8s av = *(const v8s*)&hlb[(rt2 * 16 + la) * 72 + t * 32 + lb * 8];
                v8s bv = *(const v8s*)&WcB[(size_t)(cts * 64 + lane) * 16 + t * 8];
                sa = MF(av, bv, sa);
            }
#pragma unroll
            for (int r = 0; r < 4; ++r) {
                const int n = blk * 32 + rt2 * 16 + lb * 4 + r;
                if (n < NN) {
                    if (cts == 0) Sout[(size_t)n * 20 + la] = sa[r];
                    else if (la < 4) Sout[(size_t)n * 20 + 16 + la] = sa[r];
                }
            }
        }
    }
}

// ---------------- readout: out[g] = (segsum(h)[g] @ W_out + cnt*b_out) / max(cnt,1) ----------------
__global__ __launch_bounds__(256) void k_gout(const float* __restrict__ h,
        const float* __restrict__ W, const float* __restrict__ b,
        const int* __restrict__ grp, float* __restrict__ out) {
    __shared__ float Wl[DH * DOUTC];  // 32 KB
    __shared__ float hl[4][DH];
    __shared__ float cl[4];
    for (int i = threadIdx.x; i < DH * DOUTC; i += 256) Wl[i] = W[i];
    int w = threadIdx.x >> 6, lane = threadIdx.x & 63;
    int g = blockIdx.x * 4 + w;
    int r0 = grp[g], r1 = grp[g + 1];
    float s = 0.f;
    for (int n = r0; n < r1; ++n) s += h[(size_t)n * DH + lane];
    hl[w][lane] = s;
    if (lane == 0) cl[w] = (float)(r1 - r0);
    __syncthreads();
    for (int idx = threadIdx.x; idx < 4 * DOUTC; idx += 256) {
        int gi = idx >> 7, c = idx & 127;
        float cnt = cl[gi];
        float inv = 1.f / fmaxf(cnt, 1.f);
        float acc = cnt * b[c];
        const float* hr = hl[gi];
#pragma unroll 16
        for (int k = 0; k < DH; ++k) acc += hr[k] * Wl[k * DOUTC + c];
        out[(size_t)(blockIdx.x * 4 + gi) * DOUTC + c] = acc * inv;
    }
}

// ---------------- launcher ----------------
extern "C" void kernel_launch(void* const* d_in, const int* in_sizes, int n_in,
                              void* d_out, int out_size, void* d_ws, size_t ws_size,
                              hipStream_t stream) {
    const float* x        = (const float*)d_in[0];
    const float* edge_attr= (const float*)d_in[1];
    const float* W_emb    = (const float*)d_in[2];
    const float* b_emb    = (const float*)d_in[3];
    const float* Ws       = (const float*)d_in[4];
    const float* att_src  = (const float*)d_in[5];
    const float* att_dst  = (const float*)d_in[6];
    const float* att_edge = (const float*)d_in[7];
    const float* W_edge   = (const float*)d_in[8];
    const float* bias     = (const float*)d_in[9];
    const float* bn_gamma = (const float*)d_in[10];
    const float* bn_beta  = (const float*)d_in[11];
    const float* bn_mean  = (const float*)d_in[12];
    const float* bn_var   = (const float*)d_in[13];
    const float* W_out    = (const float*)d_in[14];
    const float* b_out    = (const float*)d_in[15];
    const int*   srcp     = (const int*)d_in[16];
    const int*   dstp     = srcp + NE;
    const int*   batch    = (const int*)d_in[17];
    float* out = (float*)d_out;

    char* wsb = (char*)d_ws;
    size_t off = 0;
    auto alloc = [&](size_t bytes) -> void* {
        void* p = (void*)(wsb + off);
        off += (bytes + 255) & ~(size_t)255;
        return p;
    };
    float*  h0    = (float*)alloc((size_t)NN * DH * 4);
    float*  h1    = (float*)alloc((size_t)NN * DH * 4);
    float*  S     = (float*)alloc((size_t)NN * 20 * 4);
    __half* wraw  = (__half*)alloc((size_t)E2 * NHD * 2);
    float2* mz2   = (float2*)alloc((size_t)NN * NHD * 8);
    float*  loop  = (float*)alloc((size_t)NN * DE * 4);
    int*    cnt   = (int*)alloc((size_t)NN * 4);
    int*    rp    = (int*)alloc((size_t)(NN + 1) * 4);
    int*    cursor= (int*)alloc((size_t)NN * 4);
    int*    eidx  = (int*)alloc((size_t)E2 * 4);
    int*    scsr  = (int*)alloc((size_t)E2 * 4);
    int*    dcsr  = (int*)alloc((size_t)E2 * 4);
    int*    bsum  = (int*)alloc((size_t)SCAN_NB * 4);
    int*    grp   = (int*)alloc((size_t)(NG + 1) * 4);
    float*  WcombA= (float*)alloc((size_t)NL * DH * 20 * 4);
    float*  WeT   = (float*)alloc((size_t)NL * 160 * 4);
    unsigned short* BtA = (unsigned short*)alloc((size_t)NL * DH * 640 * 2);
    unsigned short* WcB = (unsigned short*)alloc((size_t)NL * 2 * 64 * 16 * 2);
    unsigned short* BH  = (unsigned short*)alloc((size_t)DH * 64 * 2);
    unsigned short* BL  = (unsigned short*)alloc((size_t)DH * 64 * 2);

    hipMemsetAsync(cnt,    0, (size_t)NN * 4, stream);
    hipMemsetAsync(cursor, 0, (size_t)NN * 4, stream);

    // preprocessing: CSR + self-loop attrs + graph ptrs
    k_cnt<<<(NE + 255) / 256, 256, 0, stream>>>(dstp, cnt);
    k_scan_a<<<SCAN_NB, SCAN_B, 0, stream>>>(cnt, bsum);
    k_scan_b<<<1, 64, 0, stream>>>(bsum);
    k_scan_c<<<SCAN_NB, SCAN_B, 0, stream>>>(cnt, bsum, rp);
    k_csr_fill<<<(E2 + 255) / 256, 256, 0, stream>>>(srcp, dstp, rp, cursor, eidx, scsr, dcsr);
    k_loopattr<<<(NN * DE + 255) / 256, 256, 0, stream>>>(rp, eidx, cnt, edge_attr, loop);
    k_grp<<<(NN + 255) / 256, 256, 0, stream>>>(batch, grp);

    // per-layer constants
    {
        dim3 g(6, NL);
        k_comb3<<<g, 256, 0, stream>>>(Ws, att_src, att_dst, W_edge, att_edge, WcombA, WeT);
    }
    {
        dim3 g((DH * 640 + 255) / 256, NL);
        k_prepB3<<<g, 256, 0, stream>>>(Ws, BtA);
    }
    k_wcb<<<(NL * 2 * 64 * 16 + 255) / 256, 256, 0, stream>>>(WcombA, WcB);
    k_prepWemb<<<(DH * 64 + 255) / 256, 256, 0, stream>>>(W_emb, BH, BL);

    // embedding (MFMA) + fused layer-0 scores
    k_emb<<<(NN + 63) / 64, 256, 0, stream>>>(x, BH, BL, b_emb, WcB, h0, S);

    float* hb[2] = {h0, h1};
    for (int l = 0; l < NL; ++l) {
        float* hin  = hb[l & 1];
        float* hout = hb[(l + 1) & 1];
        k_alpha<<<(E2 * NHD + 255) / 256, 256, 0, stream>>>(
            S, edge_attr, loop, WeT + (size_t)l * 160, scsr, dcsr, eidx, wraw);
        k_mz2<<<(NN * NHD + 255) / 256, 256, 0, stream>>>(wraw, rp, mz2);
        k_layer<<<(NN + 31) / 32, 512, 0, stream>>>(
            wraw, mz2, hin, rp, scsr, BtA + (size_t)l * DH * 640,
            WcB + (size_t)(l + 1 < NL ? l + 1 : 0) * 2048,
            (l + 1 < NL) ? 1 : 0, S,
            bias + l * DH, bn_gamma + l * DH, bn_beta + l * DH,
            bn_mean + l * DH, bn_var + l * DH, hout);
    }
    float* hfin = hb[NL & 1];

    // readout
    k_gout<<<NG / 4, 256, 0, stream>>>(hfin, W_out, b_out, grp, out);
}

// Round 8
// 335.914 us; speedup vs baseline: 1.0019x; 1.0019x over previous
//
#include <hip/hip_runtime.h>
#include <hip/hip_fp16.h>
#include <math.h>

// ---------------- problem constants ----------------
constexpr int NN   = 50000;          // nodes
constexpr int NE   = 150000;         // edges
constexpr int DIN  = 48;
constexpr int DH   = 64;
constexpr int DE   = 16;
constexpr int NHD  = 10;             // heads
constexpr int NL   = 3;              // layers
constexpr int DOUTC= 128;
constexpr int NG   = 4096;           // graphs
constexpr int E2   = NE + NN;        // edges incl self loops (200000)
constexpr int SCAN_B  = 256;
constexpr int SCAN_NB = (NN + SCAN_B - 1) / SCAN_B;   // 196

typedef __bf16 v8bf __attribute__((ext_vector_type(8)));
typedef short  v8s  __attribute__((ext_vector_type(8)));
typedef float  v4f  __attribute__((ext_vector_type(4)));

__device__ inline unsigned short f2bf(float f) {
    unsigned u = __builtin_bit_cast(unsigned, f);
    unsigned r = (u + 0x7FFFu + ((u >> 16) & 1u)) >> 16;
    return (unsigned short)r;
}

__device__ inline v4f MF(v8s a, v8s b, v4f c) {
    return __builtin_amdgcn_mfma_f32_16x16x32_bf16(
        __builtin_bit_cast(v8bf, a), __builtin_bit_cast(v8bf, b), c, 0, 0, 0);
}
__device__ inline v4f MFB(v8bf a, v8s b, v4f c) {
    return __builtin_amdgcn_mfma_f32_16x16x32_bf16(
        a, __builtin_bit_cast(v8bf, b), c, 0, 0, 0);
}

// broadcast a float/int from a compile-time lane (no LDS)
#define RLF(v, l) __builtin_bit_cast(float, __builtin_amdgcn_readlane(__builtin_bit_cast(int, (v)), (l)))
#define RLI(v, l) __builtin_amdgcn_readlane((v), (l))

// ---------------- preprocessing ----------------
__global__ void k_cnt(const int* __restrict__ dst, int* __restrict__ cnt) {
    int e = blockIdx.x * blockDim.x + threadIdx.x;
    if (e < NE) atomicAdd(&cnt[dst[e]], 1);
}

__global__ void k_scan_a(const int* __restrict__ cnt, int* __restrict__ bsum) {
    __shared__ int s[SCAN_B];
    int i = blockIdx.x * SCAN_B + threadIdx.x;
    s[threadIdx.x] = (i < NN) ? (cnt[i] + 1) : 0;   // +1 = self loop
    __syncthreads();
    for (int off = SCAN_B / 2; off > 0; off >>= 1) {
        if (threadIdx.x < off) s[threadIdx.x] += s[threadIdx.x + off];
        __syncthreads();
    }
    if (threadIdx.x == 0) bsum[blockIdx.x] = s[0];
}

__global__ void k_scan_b(int* __restrict__ bsum) {
    if (threadIdx.x == 0 && blockIdx.x == 0) {
        int acc = 0;
        for (int i = 0; i < SCAN_NB; ++i) { int v = bsum[i]; bsum[i] = acc; acc += v; }
    }
}

__global__ void k_scan_c(const int* __restrict__ cnt, const int* __restrict__ bsum,
                         int* __restrict__ rp) {
    __shared__ int s[SCAN_B];
    int i = blockIdx.x * SCAN_B + threadIdx.x;
    int v = (i < NN) ? (cnt[i] + 1) : 0;
    s[threadIdx.x] = v;
    __syncthreads();
    for (int off = 1; off < SCAN_B; off <<= 1) {
        int t = (threadIdx.x >= off) ? s[threadIdx.x - off] : 0;
        __syncthreads();
        s[threadIdx.x] += t;
        __syncthreads();
    }
    if (i < NN) {
        int excl = bsum[blockIdx.x] + s[threadIdx.x] - v;
        rp[i] = excl;
        if (i == NN - 1) rp[NN] = excl + v;
    }
}

__global__ void k_csr_fill(const int* __restrict__ src, const int* __restrict__ dst,
                           const int* __restrict__ rp, int* __restrict__ cursor,
                           int* __restrict__ eidx, int* __restrict__ scsr,
                           int* __restrict__ dcsr) {
    int e = blockIdx.x * blockDim.x + threadIdx.x;
    if (e >= E2) return;
    int d  = (e < NE) ? dst[e] : (e - NE);
    int sn = (e < NE) ? src[e] : d;
    int pos = atomicAdd(&cursor[d], 1);
    int s = rp[d] + pos;
    eidx[s] = e; scsr[s] = sn; dcsr[s] = d;
}

// self-loop attr = mean of real incoming edge attrs (no atomics, via CSR)
__global__ void k_loopattr(const int* __restrict__ rp, const int* __restrict__ eidx,
                           const int* __restrict__ cnt, const float* __restrict__ ea,
                           float* __restrict__ loop) {
    int tid = blockIdx.x * blockDim.x + threadIdx.x;
    if (tid >= NN * DE) return;
    int n = tid >> 4, d = tid & 15;
    int r0 = rp[n], r1 = rp[n + 1];
    float s = 0.f;
    for (int t = r0; t < r1; ++t) {
        int eid = eidx[t];
        if (eid < NE) s += ea[(size_t)eid * DE + d];
    }
    int c = cnt[n];
    loop[tid] = s * ((c > 1) ? (1.0f / (float)c) : 1.0f);
}

// graph row pointers from sorted batch ids
__global__ void k_grp(const int* __restrict__ batch, int* __restrict__ grp) {
    int n = blockIdx.x * blockDim.x + threadIdx.x;
    if (n >= NN) return;
    int b = batch[n];
    int pb = (n == 0) ? -1 : batch[n - 1];
    for (int g = pb + 1; g <= b; ++g) grp[g] = n;
    if (n == NN - 1) for (int g = b + 1; g <= NG; ++g) grp[g] = NN;
}

// ---------------- W_emb hi/lo bf16 in B-frag layout: BH/BL[c*64+k] ----------------
__global__ void k_prepWemb(const float* __restrict__ W, unsigned short* __restrict__ BH,
                           unsigned short* __restrict__ BL) {
    int tid = blockIdx.x * blockDim.x + threadIdx.x;
    if (tid >= DH * 64) return;
    int c = tid >> 6, k = tid & 63;
    float v = (k < DIN) ? W[(size_t)k * DH + c] : 0.f;
    __bf16 hi = (__bf16)v;
    BH[tid] = __builtin_bit_cast(unsigned short, hi);
    BL[tid] = __builtin_bit_cast(unsigned short, (__bf16)(v - (float)hi));
}

// ---------------- embedding via MFMA (hi/lo split) + fused layer-0 scores ----------------
// 256 threads = 4 waves; 64 nodes/block; wave w owns row-tile w (16 nodes).
__global__ __launch_bounds__(256) void k_emb(const float* __restrict__ x,
        const unsigned short* __restrict__ BH, const unsigned short* __restrict__ BL,
        const float* __restrict__ bemb, const unsigned short* __restrict__ WcB,
        float* __restrict__ h, float* __restrict__ S) {
    __shared__ __align__(16) unsigned short hlb[4][16 * 72];
    const int tid = threadIdx.x;
    const int w = tid >> 6, lane = tid & 63;
    const int la = lane & 15, lb = lane >> 4;
    const int rowbase = blockIdx.x * 64 + w * 16;
    const int nA = rowbase + la;

    v8bf ah[2], al[2];
#pragma unroll
    for (int ks = 0; ks < 2; ++ks) {
        const int k0 = ks * 32 + lb * 8;
        float xv[8];
        if (nA < NN && k0 < DIN) {
            const float* xp = x + (size_t)nA * DIN + k0;
            float4 v0 = *(const float4*)xp;
            float4 v1 = *(const float4*)(xp + 4);
            xv[0]=v0.x; xv[1]=v0.y; xv[2]=v0.z; xv[3]=v0.w;
            xv[4]=v1.x; xv[5]=v1.y; xv[6]=v1.z; xv[7]=v1.w;
        } else {
#pragma unroll
            for (int e = 0; e < 8; ++e) xv[e] = 0.f;
        }
#pragma unroll
        for (int e = 0; e < 8; ++e) {
            __bf16 hi = (__bf16)xv[e];
            ah[ks][e] = hi;
            al[ks][e] = (__bf16)(xv[e] - (float)hi);
        }
    }
    v4f acc[4];
#pragma unroll
    for (int ct = 0; ct < 4; ++ct) acc[ct] = (v4f){0.f, 0.f, 0.f, 0.f};
#pragma unroll
    for (int ct = 0; ct < 4; ++ct) {
#pragma unroll
        for (int ks = 0; ks < 2; ++ks) {
            const int boff = (ct * 16 + la) * 64 + ks * 32 + lb * 8;
            v8s bh = *(const v8s*)&BH[boff];
            v8s bl = *(const v8s*)&BL[boff];
            acc[ct] = MFB(ah[ks], bh, acc[ct]);
            acc[ct] = MFB(al[ks], bh, acc[ct]);
            acc[ct] = MFB(ah[ks], bl, acc[ct]);
        }
    }
    // epilogue: + b_emb, write h, stash bf16 tile
#pragma unroll
    for (int ct = 0; ct < 4; ++ct) {
        const int c = ct * 16 + la;
        const float bi = bemb[c];
#pragma unroll
        for (int r = 0; r < 4; ++r) {
            const int row = lb * 4 + r;
            const int n = rowbase + row;
            float v = acc[ct][r] + bi;
            if (n < NN) h[(size_t)n * DH + c] = v;
            hlb[w][row * 72 + c] = f2bf(v);
        }
    }
    __syncthreads();
    // layer-0 scores: S[16 rows][20] per wave via 2 col-tiles
    v4f s0 = {0.f,0.f,0.f,0.f}, s1 = {0.f,0.f,0.f,0.f};
#pragma unroll
    for (int t = 0; t < 2; ++t) {
        v8s av = *(const v8s*)&hlb[w][la * 72 + t * 32 + lb * 8];
        v8s b0 = *(const v8s*)&WcB[(size_t)(lane) * 16 + t * 8];
        v8s b1 = *(const v8s*)&WcB[(size_t)(64 + lane) * 16 + t * 8];
        s0 = MF(av, b0, s0);
        s1 = MF(av, b1, s1);
    }
#pragma unroll
    for (int r = 0; r < 4; ++r) {
        const int n = rowbase + lb * 4 + r;
        if (n < NN) {
            S[(size_t)n * 20 + la] = s0[r];
            if (la < 4) S[(size_t)n * 20 + 16 + la] = s1[r];
        }
    }
}

// ---------------- all-layer combined attention weights (+ transposed WeT) ----------------
__global__ void k_comb3(const float* __restrict__ Ws, const float* __restrict__ asrc,
                        const float* __restrict__ adst, const float* __restrict__ We_in,
                        const float* __restrict__ aedge, float* __restrict__ Wcomb,
                        float* __restrict__ WeT) {
    int layer = blockIdx.y;
    int tid = blockIdx.x * blockDim.x + threadIdx.x;
    if (tid < DH * 2 * NHD) {                      // 1280
        int k = tid / 20, j = tid % 20;
        int hh = j % NHD;
        const float* a = ((j < NHD) ? asrc : adst) + (size_t)layer * NHD * DH + hh * DH;
        const float* w = Ws + ((size_t)layer * DH + k) * (NHD * DH) + hh * DH;
        float s = 0.f;
#pragma unroll
        for (int f = 0; f < DH; ++f) s += w[f] * a[f];
        Wcomb[layer * 1280 + tid] = s;
    } else if (tid < DH * 2 * NHD + DE * NHD) {    // +160
        int t = tid - DH * 2 * NHD;
        int d = t / NHD, hh = t % NHD;
        const float* a = aedge + (size_t)layer * NHD * DH + hh * DH;
        const float* w = We_in + ((size_t)layer * DE + d) * (NHD * DH) + hh * DH;
        float s = 0.f;
#pragma unroll
        for (int f = 0; f < DH; ++f) s += w[f] * a[f];
        WeT[layer * 160 + hh * 16 + d] = s;        // [h][d] transposed
    }
}

// ---------------- Bt[l][f][j'] with j' = k*10+q : B[j'][f] = Ws[l][k][q*64+f]*0.1, bf16 ----------------
__global__ void k_prepB3(const float* __restrict__ Ws, unsigned short* __restrict__ Bt) {
    int layer = blockIdx.y;
    int tid = blockIdx.x * blockDim.x + threadIdx.x;
    if (tid >= DH * 640) return;
    int f = tid / 640, jp = tid % 640;
    int k = jp / 10, q = jp % 10;
    float v = Ws[(size_t)layer * DH * 640 + (size_t)k * 640 + q * 64 + f] * 0.1f;
    Bt[(size_t)layer * DH * 640 + tid] = f2bf(v);
}

// ---------------- Wcomb in MFMA B-fragment layout (bf16), per layer, 2 col-tiles ----------------
__global__ void k_wcb(const float* __restrict__ Wcomb, unsigned short* __restrict__ WcB) {
    int tid = blockIdx.x * blockDim.x + threadIdx.x;
    if (tid >= NL * 2 * 64 * 16) return;
    int l = tid / 2048, r = tid % 2048;
    int tile = r / 1024, rr = r % 1024;
    int ln = rr / 16, idx = rr % 16;
    int t = idx / 8, e = idx % 8;
    int k = t * 32 + (ln >> 4) * 8 + e;
    int jc = ln & 15;
    float v = 0.f;
    if (tile == 0 || jc < 4) v = Wcomb[l * 1280 + k * 20 + tile * 16 + jc];
    WcB[tid] = f2bf(v);
}

// ---------------- alpha per (slot, head): fully parallel, a_e inline, fp16 out ----------------
__global__ void k_alpha(const float* __restrict__ S, const float* __restrict__ ea,
                        const float* __restrict__ loop, const float* __restrict__ WeT,
                        const int* __restrict__ scsr, const int* __restrict__ dcsr,
                        const int* __restrict__ eidx, __half* __restrict__ wraw) {
    int tid = blockIdx.x * blockDim.x + threadIdx.x;
    if (tid >= E2 * NHD) return;
    int s = tid / NHD, h = tid - (tid / NHD) * NHD;
    int sn = scsr[s], dn = dcsr[s], eid = eidx[s];
    const float* ar = (eid < NE) ? (ea + (size_t)eid * DE) : (loop + (size_t)(eid - NE) * DE);
    const float* wt = WeT + h * 16;
    float4 a0 = *(const float4*)(ar + 0);
    float4 a1 = *(const float4*)(ar + 4);
    float4 a2 = *(const float4*)(ar + 8);
    float4 a3 = *(const float4*)(ar + 12);
    float4 w0 = *(const float4*)(wt + 0);
    float4 w1 = *(const float4*)(wt + 4);
    float4 w2 = *(const float4*)(wt + 8);
    float4 w3 = *(const float4*)(wt + 12);
    float aev = a0.x*w0.x + a0.y*w0.y + a0.z*w0.z + a0.w*w0.w
              + a1.x*w1.x + a1.y*w1.y + a1.z*w1.z + a1.w*w1.w
              + a2.x*w2.x + a2.y*w2.y + a2.z*w2.z + a2.w*w2.w
              + a3.x*w3.x + a3.y*w3.y + a3.z*w3.z + a3.w*w3.w;
    float a = S[(size_t)sn * 20 + h] + S[(size_t)dn * 20 + 10 + h] + aev;
    a = (a > 0.f) ? a : 0.2f * a;
    wraw[tid] = (__half)a;
}

// ---------------- per-(node,head): streaming max + 1/z over fp16 alphas ----------------
__global__ void k_mz2(const __half* __restrict__ wraw, const int* __restrict__ rp,
                      float2* __restrict__ mz2) {
    int tid = blockIdx.x * blockDim.x + threadIdx.x;
    if (tid >= NN * NHD) return;
    int n = tid / NHD, h = tid - (tid / NHD) * NHD;
    int r0 = rp[n], r1 = rp[n + 1];
    float m = -1e30f;
    for (int s = r0; s < r1; ++s) m = fmaxf(m, (float)wraw[(size_t)s * NHD + h]);
    float z = 0.f;
    for (int s = r0; s < r1; ++s) z += __expf((float)wraw[(size_t)s * NHD + h] - m);
    mz2[tid] = make_float2(m, 1.f / z);
}

// ---------------- fused layer: reg-only agg -> LDS G tile -> MFMA -> epilogue -> next-S ----------------
// 512 threads = 8 waves, 32 nodes/block; wave w owns nodes w*4..w*4+3 in Phase A.
__global__ __launch_bounds__(512) void k_layer(
        const __half* __restrict__ wraw, const float2* __restrict__ mz2,
        const float* __restrict__ hin, const int* __restrict__ rp,
        const int* __restrict__ scsr, const unsigned short* __restrict__ Bt,
        const unsigned short* __restrict__ WcB, int do_s, float* __restrict__ Sout,
        const float* __restrict__ bias, const float* __restrict__ gam,
        const float* __restrict__ bet, const float* __restrict__ mean,
        const float* __restrict__ var, float* __restrict__ hout) {
    __shared__ __align__(16) unsigned short Gl[32 * 648];   // 41472 B

    const int tid = threadIdx.x;
    const int w = tid >> 6, lane = tid & 63;
    const int el = lane / NHD, hh = lane - el * NHD;  // valid for lane<60
    const int blk = blockIdx.x;
    const int nb4 = blk * 32 + w * 4;

    // ---- Phase A: stage softmax weights + src for 4 nodes ----
    int r0a[4], dga[4]; float wreg[4]; int sreg[4];
#pragma unroll
    for (int i = 0; i < 4; ++i) {
        const int n = nb4 + i;
        int r0 = 0, dg = 0;
        if (n < NN) { r0 = rp[n]; dg = rp[n + 1] - r0; }
        r0a[i] = r0; dga[i] = dg;
        float wv = 0.f;
        if (lane < 60 && el < dg) {
            float a = (float)wraw[(size_t)r0 * NHD + lane];
            float2 mz = mz2[(size_t)n * NHD + hh];
            wv = __expf(a - mz.x) * mz.y;
        }
        wreg[i] = wv;
        sreg[i] = (lane < 6 && lane < dg) ? scsr[r0 + lane] : 0;
    }
    float hv[4][6];
#pragma unroll
    for (int i = 0; i < 4; ++i) {
#pragma unroll
        for (int j = 0; j < 6; ++j) {
            int sv = RLI(sreg[i], j);
            hv[i][j] = hin[(size_t)sv * DH + lane];
        }
    }
#pragma unroll
    for (int i = 0; i < 4; ++i) {
        float g[NHD];
#pragma unroll
        for (int q = 0; q < NHD; ++q) g[q] = 0.f;
#pragma unroll
        for (int j = 0; j < 6; ++j) {
#pragma unroll
            for (int q = 0; q < NHD; ++q)
                g[q] = fmaf(RLF(wreg[i], j * 10 + q), hv[i][j], g[q]);
        }
        // tail chunks (deg > 6)
        const int n = nb4 + i;
        for (int c0 = 6; c0 < dga[i]; c0 += 6) {
            float w2 = (lane < 60 && el < dga[i] - c0)
                       ? __expf((float)wraw[(size_t)(r0a[i] + c0) * NHD + lane]
                                - mz2[(size_t)n * NHD + hh].x) * mz2[(size_t)n * NHD + hh].y
                       : 0.f;
            int s2 = (lane < 6 && c0 + lane < dga[i]) ? scsr[r0a[i] + c0 + lane] : 0;
            float hv2[6];
#pragma unroll
            for (int j = 0; j < 6; ++j) {
                int sv = RLI(s2, j);
                hv2[j] = hin[(size_t)sv * DH + lane];
            }
#pragma unroll
            for (int j = 0; j < 6; ++j)
#pragma unroll
                for (int q = 0; q < NHD; ++q)
                    g[q] = fmaf(RLF(w2, j * 10 + q), hv2[j], g[q]);
        }
        // write G row: G[li][k*10+q], lane=k holds 10 consecutive bf16 -> 5 packed b32
        const int li = w * 4 + i;
        const int base = li * 648 + lane * 10;
#pragma unroll
        for (int p = 0; p < 5; ++p) {
            unsigned u = (unsigned)f2bf(g[2 * p]) | ((unsigned)f2bf(g[2 * p + 1]) << 16);
            *(unsigned*)&Gl[base + 2 * p] = u;
        }
    }
    __syncthreads();

    // ---- Phase B: xc = G @ B, 8 tiles (2 row x 4 col) across 8 waves ----
    const int rt = w & 1, ct = w >> 1;
    const int la = lane & 15, lb = lane >> 4;
    v4f acc = {0.f, 0.f, 0.f, 0.f};
    const size_t brow = (size_t)(ct * 16 + la) * 640;
#pragma unroll 5
    for (int t = 0; t < 20; ++t) {
        const int koff = t * 32 + lb * 8;
        v8s av = *(const v8s*)&Gl[(rt * 16 + la) * 648 + koff];
        v8s bv = *(const v8s*)&Bt[brow + koff];
        acc = MF(av, bv, acc);
    }
    __syncthreads();      // all Gl reads done; epilogue reuses Gl as bf16 h-tile

    // ---- epilogue: bias + BN + gelu + residual; stash hout tile (bf16) in LDS ----
    unsigned short* hlb = Gl;           // [32][72] bf16 (alias)
    const int f = ct * 16 + la;
    const float bi = bias[f], gm = gam[f], bt_ = bet[f], mu = mean[f];
    const float iv = rsqrtf(var[f] + 1e-5f);
#pragma unroll
    for (int r = 0; r < 4; ++r) {
        const int local = rt * 16 + lb * 4 + r;
        const int n = blk * 32 + local;
        float v = acc[r] + bi;
        v = (v - mu) * gm * iv + bt_;
        v = 0.5f * v * (1.0f + erff(v * 0.70710678118654752f));
        float hnew = v;
        if (n < NN) {
            hnew += hin[(size_t)n * DH + f];
            hout[(size_t)n * DH + f] = hnew;
        }
        hlb[local * 72 + f] = f2bf(hnew);
    }

    // ---- fused next-layer scores ----
    if (do_s) {
        __syncthreads();
        if (w < 4) {
            const int rt2 = w >> 1, cts = w & 1;
            v4f sa = {0.f, 0.f, 0.f, 0.f};
#pragma unroll
            for (int t = 0; t < 2; ++t) {
                v8s av = *(const v8s*)&hlb[(rt2 * 16 + la) * 72 + t * 32 + lb * 8];
                v8s bv = *(const v8s*)&WcB[(size_t)(cts * 64 + lane) * 16 + t * 8];
                sa = MF(av, bv, sa);
            }
#pragma unroll
            for (int r = 0; r < 4; ++r) {
                const int n = blk * 32 + rt2 * 16 + lb * 4 + r;
                if (n < NN) {
                    if (cts == 0) Sout[(size_t)n * 20 + la] = sa[r];
                    else if (la < 4) Sout[(size_t)n * 20 + 16 + la] = sa[r];
                }
            }
        }
    }
}

// ---------------- readout: out[g] = (segsum(h)[g] @ W_out + cnt*b_out) / max(cnt,1) ----------------
__global__ __launch_bounds__(256) void k_gout(const float* __restrict__ h,
        const float* __restrict__ W, const float* __restrict__ b,
        const int* __restrict__ grp, float* __restrict__ out) {
    __shared__ float Wl[DH * DOUTC];  // 32 KB
    __shared__ float hl[4][DH];
    __shared__ float cl[4];
    for (int i = threadIdx.x; i < DH * DOUTC; i += 256) Wl[i] = W[i];
    int w = threadIdx.x >> 6, lane = threadIdx.x & 63;
    int g = blockIdx.x * 4 + w;
    int r0 = grp[g], r1 = grp[g + 1];
    float s = 0.f;
    for (int n = r0; n < r1; ++n) s += h[(size_t)n * DH + lane];
    hl[w][lane] = s;
    if (lane == 0) cl[w] = (float)(r1 - r0);
    __syncthreads();
    for (int idx = threadIdx.x; idx < 4 * DOUTC; idx += 256) {
        int gi = idx >> 7, c = idx & 127;
        float cnt = cl[gi];
        float inv = 1.f / fmaxf(cnt, 1.f);
        float acc = cnt * b[c];
        const float* hr = hl[gi];
#pragma unroll 16
        for (int k = 0; k < DH; ++k) acc += hr[k] * Wl[k * DOUTC + c];
        out[(size_t)(blockIdx.x * 4 + gi) * DOUTC + c] = acc * inv;
    }
}

// ---------------- launcher ----------------
extern "C" void kernel_launch(void* const* d_in, const int* in_sizes, int n_in,
                              void* d_out, int out_size, void* d_ws, size_t ws_size,
                              hipStream_t stream) {
    const float* x        = (const float*)d_in[0];
    const float* edge_attr= (const float*)d_in[1];
    const float* W_emb    = (const float*)d_in[2];
    const float* b_emb    = (const float*)d_in[3];
    const float* Ws       = (const float*)d_in[4];
    const float* att_src  = (const float*)d_in[5];
    const float* att_dst  = (const float*)d_in[6];
    const float* att_edge = (const float*)d_in[7];
    const float* W_edge   = (const float*)d_in[8];
    const float* bias     = (const float*)d_in[9];
    const float* bn_gamma = (const float*)d_in[10];
    const float* bn_beta  = (const float*)d_in[11];
    const float* bn_mean  = (const float*)d_in[12];
    const float* bn_var   = (const float*)d_in[13];
    const float* W_out    = (const float*)d_in[14];
    const float* b_out    = (const float*)d_in[15];
    const int*   srcp     = (const int*)d_in[16];
    const int*   dstp     = srcp + NE;
    const int*   batch    = (const int*)d_in[17];
    float* out = (float*)d_out;

    char* wsb = (char*)d_ws;
    size_t off = 0;
    auto alloc = [&](size_t bytes) -> void* {
        void* p = (void*)(wsb + off);
        off += (bytes + 255) & ~(size_t)255;
        return p;
    };
    float*  h0    = (float*)alloc((size_t)NN * DH * 4);
    float*  h1    = (float*)alloc((size_t)NN * DH * 4);
    float*  S     = (float*)alloc((size_t)NN * 20 * 4);
    __half* wraw  = (__half*)alloc((size_t)E2 * NHD * 2);
    float2* mz2   = (float2*)alloc((size_t)NN * NHD * 8);
    float*  loop  = (float*)alloc((size_t)NN * DE * 4);
    int*    cnt   = (int*)alloc((size_t)NN * 4);
    int*    rp    = (int*)alloc((size_t)(NN + 1) * 4);
    int*    cursor= (int*)alloc((size_t)NN * 4);
    int*    eidx  = (int*)alloc((size_t)E2 * 4);
    int*    scsr  = (int*)alloc((size_t)E2 * 4);
    int*    dcsr  = (int*)alloc((size_t)E2 * 4);
    int*    bsum  = (int*)alloc((size_t)SCAN_NB * 4);
    int*    grp   = (int*)alloc((size_t)(NG + 1) * 4);
    float*  WcombA= (float*)alloc((size_t)NL * DH * 20 * 4);
    float*  WeT   = (float*)alloc((size_t)NL * 160 * 4);
    unsigned short* BtA = (unsigned short*)alloc((size_t)NL * DH * 640 * 2);
    unsigned short* WcB = (unsigned short*)alloc((size_t)NL * 2 * 64 * 16 * 2);
    unsigned short* BH  = (unsigned short*)alloc((size_t)DH * 64 * 2);
    unsigned short* BL  = (unsigned short*)alloc((size_t)DH * 64 * 2);

    hipMemsetAsync(cnt,    0, (size_t)NN * 4, stream);
    hipMemsetAsync(cursor, 0, (size_t)NN * 4, stream);

    // preprocessing: CSR + self-loop attrs + graph ptrs
    k_cnt<<<(NE + 255) / 256, 256, 0, stream>>>(dstp, cnt);
    k_scan_a<<<SCAN_NB, SCAN_B, 0, stream>>>(cnt, bsum);
    k_scan_b<<<1, 64, 0, stream>>>(bsum);
    k_scan_c<<<SCAN_NB, SCAN_B, 0, stream>>>(cnt, bsum, rp);
    k_csr_fill<<<(E2 + 255) / 256, 256, 0, stream>>>(srcp, dstp, rp, cursor, eidx, scsr, dcsr);
    k_loopattr<<<(NN * DE + 255) / 256, 256, 0, stream>>>(rp, eidx, cnt, edge_attr, loop);
    k_grp<<<(NN + 255) / 256, 256, 0, stream>>>(batch, grp);

    // per-layer constants
    {
        dim3 g(6, NL);
        k_comb3<<<g, 256, 0, stream>>>(Ws, att_src, att_dst, W_edge, att_edge, WcombA, WeT);
    }
    {
        dim3 g((DH * 640 + 255) / 256, NL);
        k_prepB3<<<g, 256, 0, stream>>>(Ws, BtA);
    }
    k_wcb<<<(NL * 2 * 64 * 16 + 255) / 256, 256, 0, stream>>>(WcombA, WcB);
    k_prepWemb<<<(DH * 64 + 255) / 256, 256, 0, stream>>>(W_emb, BH, BL);

    // embedding (MFMA) + fused layer-0 scores
    k_emb<<<(NN + 63) / 64, 256, 0, stream>>>(x, BH, BL, b_emb, WcB, h0, S);

    float* hb[2] = {h0, h1};
    for (int l = 0; l < NL; ++l) {
        float* hin  = hb[l & 1];
        float* hout = hb[(l + 1) & 1];
        k_alpha<<<(E2 * NHD + 255) / 256, 256, 0, stream>>>(
            S, edge_attr, loop, WeT + (size_t)l * 160, scsr, dcsr, eidx, wraw);
        k_mz2<<<(NN * NHD + 255) / 256, 256, 0, stream>>>(wraw, rp, mz2);
        k_layer<<<(NN + 31) / 32, 512, 0, stream>>>(
            wraw, mz2, hin, rp, scsr, BtA + (size_t)l * DH * 640,
            WcB + (size_t)(l + 1 < NL ? l + 1 : 0) * 2048,
            (l + 1 < NL) ? 1 : 0, S,
            bias + l * DH, bn_gamma + l * DH, bn_beta + l * DH,
            bn_mean + l * DH, bn_var + l * DH, hout);
    }
    float* hfin = hb[NL & 1];

    // readout
    k_gout<<<NG / 4, 256, 0, stream>>>(hfin, W_out, b_out, grp, out);
}

// Round 9
// 248.449 us; speedup vs baseline: 1.3546x; 1.3520x over previous
//
#include <hip/hip_runtime.h>
#include <hip/hip_fp16.h>
#include <math.h>

// ---------------- problem constants ----------------
constexpr int NN   = 50000;          // nodes
constexpr int NE   = 150000;         // edges
constexpr int DIN  = 48;
constexpr int DH   = 64;
constexpr int DE   = 16;
constexpr int NHD  = 10;             // heads
constexpr int NL   = 3;              // layers
constexpr int DOUTC= 128;
constexpr int NG   = 4096;           // graphs
constexpr int E2   = NE + NN;        // edges incl self loops (200000)
constexpr int SCAN_B  = 256;
constexpr int SCAN_NB = (NN + SCAN_B - 1) / SCAN_B;   // 196

typedef __bf16 v8bf __attribute__((ext_vector_type(8)));
typedef short  v8s  __attribute__((ext_vector_type(8)));
typedef float  v4f  __attribute__((ext_vector_type(4)));

__device__ inline unsigned short f2bf(float f) {
    unsigned u = __builtin_bit_cast(unsigned, f);
    unsigned r = (u + 0x7FFFu + ((u >> 16) & 1u)) >> 16;
    return (unsigned short)r;
}

__device__ inline v4f MF(v8s a, v8s b, v4f c) {
    return __builtin_amdgcn_mfma_f32_16x16x32_bf16(
        __builtin_bit_cast(v8bf, a), __builtin_bit_cast(v8bf, b), c, 0, 0, 0);
}
__device__ inline v4f MFB(v8bf a, v8s b, v4f c) {
    return __builtin_amdgcn_mfma_f32_16x16x32_bf16(
        a, __builtin_bit_cast(v8bf, b), c, 0, 0, 0);
}

// broadcast a float/int from a compile-time lane (no LDS)
#define RLF(v, l) __builtin_bit_cast(float, __builtin_amdgcn_readlane(__builtin_bit_cast(int, (v)), (l)))
#define RLI(v, l) __builtin_amdgcn_readlane((v), (l))

// ---------------- preprocessing ----------------
__global__ void k_cnt(const int* __restrict__ dst, int* __restrict__ cnt) {
    int e = blockIdx.x * blockDim.x + threadIdx.x;
    if (e < NE) atomicAdd(&cnt[dst[e]], 1);
}

__global__ void k_scan_a(const int* __restrict__ cnt, int* __restrict__ bsum) {
    __shared__ int s[SCAN_B];
    int i = blockIdx.x * SCAN_B + threadIdx.x;
    s[threadIdx.x] = (i < NN) ? (cnt[i] + 1) : 0;   // +1 = self loop
    __syncthreads();
    for (int off = SCAN_B / 2; off > 0; off >>= 1) {
        if (threadIdx.x < off) s[threadIdx.x] += s[threadIdx.x + off];
        __syncthreads();
    }
    if (threadIdx.x == 0) bsum[blockIdx.x] = s[0];
}

__global__ void k_scan_b(int* __restrict__ bsum) {
    if (threadIdx.x == 0 && blockIdx.x == 0) {
        int acc = 0;
        for (int i = 0; i < SCAN_NB; ++i) { int v = bsum[i]; bsum[i] = acc; acc += v; }
    }
}

__global__ void k_scan_c(const int* __restrict__ cnt, const int* __restrict__ bsum,
                         int* __restrict__ rp) {
    __shared__ int s[SCAN_B];
    int i = blockIdx.x * SCAN_B + threadIdx.x;
    int v = (i < NN) ? (cnt[i] + 1) : 0;
    s[threadIdx.x] = v;
    __syncthreads();
    for (int off = 1; off < SCAN_B; off <<= 1) {
        int t = (threadIdx.x >= off) ? s[threadIdx.x - off] : 0;
        __syncthreads();
        s[threadIdx.x] += t;
        __syncthreads();
    }
    if (i < NN) {
        int excl = bsum[blockIdx.x] + s[threadIdx.x] - v;
        rp[i] = excl;
        if (i == NN - 1) rp[NN] = excl + v;
    }
}

__global__ void k_csr_fill(const int* __restrict__ src, const int* __restrict__ dst,
                           const int* __restrict__ rp, int* __restrict__ cursor,
                           int* __restrict__ eidx, int* __restrict__ scsr,
                           int* __restrict__ dcsr) {
    int e = blockIdx.x * blockDim.x + threadIdx.x;
    if (e >= E2) return;
    int d  = (e < NE) ? dst[e] : (e - NE);
    int sn = (e < NE) ? src[e] : d;
    int pos = atomicAdd(&cursor[d], 1);
    int s = rp[d] + pos;
    eidx[s] = e; scsr[s] = sn; dcsr[s] = d;
}

// per-node packed metadata: [src0..src5, deg, r0]
__global__ void k_snl6(const int* __restrict__ rp, const int* __restrict__ scsr,
                       int* __restrict__ snl6) {
    int tid = blockIdx.x * blockDim.x + threadIdx.x;
    if (tid >= NN * 8) return;
    int n = tid >> 3, j = tid & 7;
    int r0 = rp[n], deg = rp[n + 1] - r0;
    int v;
    if (j < 6)       v = (j < deg) ? scsr[r0 + j] : 0;
    else if (j == 6) v = deg;
    else             v = r0;
    snl6[tid] = v;
}

// self-loop attr = mean of real incoming edge attrs (no atomics, via CSR)
__global__ void k_loopattr(const int* __restrict__ rp, const int* __restrict__ eidx,
                           const int* __restrict__ cnt, const float* __restrict__ ea,
                           float* __restrict__ loop) {
    int tid = blockIdx.x * blockDim.x + threadIdx.x;
    if (tid >= NN * DE) return;
    int n = tid >> 4, d = tid & 15;
    int r0 = rp[n], r1 = rp[n + 1];
    float s = 0.f;
    for (int t = r0; t < r1; ++t) {
        int eid = eidx[t];
        if (eid < NE) s += ea[(size_t)eid * DE + d];
    }
    int c = cnt[n];
    loop[tid] = s * ((c > 1) ? (1.0f / (float)c) : 1.0f);
}

// graph row pointers from sorted batch ids
__global__ void k_grp(const int* __restrict__ batch, int* __restrict__ grp) {
    int n = blockIdx.x * blockDim.x + threadIdx.x;
    if (n >= NN) return;
    int b = batch[n];
    int pb = (n == 0) ? -1 : batch[n - 1];
    for (int g = pb + 1; g <= b; ++g) grp[g] = n;
    if (n == NN - 1) for (int g = b + 1; g <= NG; ++g) grp[g] = NN;
}

// ---------------- W_emb hi/lo bf16 in B-frag layout: BH/BL[c*64+k] ----------------
__global__ void k_prepWemb(const float* __restrict__ W, unsigned short* __restrict__ BH,
                           unsigned short* __restrict__ BL) {
    int tid = blockIdx.x * blockDim.x + threadIdx.x;
    if (tid >= DH * 64) return;
    int c = tid >> 6, k = tid & 63;
    float v = (k < DIN) ? W[(size_t)k * DH + c] : 0.f;
    __bf16 hi = (__bf16)v;
    BH[tid] = __builtin_bit_cast(unsigned short, hi);
    BL[tid] = __builtin_bit_cast(unsigned short, (__bf16)(v - (float)hi));
}

// ---------------- embedding via MFMA (hi/lo split) + fused layer-0 scores ----------------
__global__ __launch_bounds__(256) void k_emb(const float* __restrict__ x,
        const unsigned short* __restrict__ BH, const unsigned short* __restrict__ BL,
        const float* __restrict__ bemb, const unsigned short* __restrict__ WcB,
        float* __restrict__ h, float* __restrict__ S) {
    __shared__ __align__(16) unsigned short hlb[4][16 * 72];
    const int tid = threadIdx.x;
    const int w = tid >> 6, lane = tid & 63;
    const int la = lane & 15, lb = lane >> 4;
    const int rowbase = blockIdx.x * 64 + w * 16;
    const int nA = rowbase + la;

    v8bf ah[2], al[2];
#pragma unroll
    for (int ks = 0; ks < 2; ++ks) {
        const int k0 = ks * 32 + lb * 8;
        float xv[8];
        if (nA < NN && k0 < DIN) {
            const float* xp = x + (size_t)nA * DIN + k0;
            float4 v0 = *(const float4*)xp;
            float4 v1 = *(const float4*)(xp + 4);
            xv[0]=v0.x; xv[1]=v0.y; xv[2]=v0.z; xv[3]=v0.w;
            xv[4]=v1.x; xv[5]=v1.y; xv[6]=v1.z; xv[7]=v1.w;
        } else {
#pragma unroll
            for (int e = 0; e < 8; ++e) xv[e] = 0.f;
        }
#pragma unroll
        for (int e = 0; e < 8; ++e) {
            __bf16 hi = (__bf16)xv[e];
            ah[ks][e] = hi;
            al[ks][e] = (__bf16)(xv[e] - (float)hi);
        }
    }
    v4f acc[4];
#pragma unroll
    for (int ct = 0; ct < 4; ++ct) acc[ct] = (v4f){0.f, 0.f, 0.f, 0.f};
#pragma unroll
    for (int ct = 0; ct < 4; ++ct) {
#pragma unroll
        for (int ks = 0; ks < 2; ++ks) {
            const int boff = (ct * 16 + la) * 64 + ks * 32 + lb * 8;
            v8s bh = *(const v8s*)&BH[boff];
            v8s bl = *(const v8s*)&BL[boff];
            acc[ct] = MFB(ah[ks], bh, acc[ct]);
            acc[ct] = MFB(al[ks], bh, acc[ct]);
            acc[ct] = MFB(ah[ks], bl, acc[ct]);
        }
    }
#pragma unroll
    for (int ct = 0; ct < 4; ++ct) {
        const int c = ct * 16 + la;
        const float bi = bemb[c];
#pragma unroll
        for (int r = 0; r < 4; ++r) {
            const int row = lb * 4 + r;
            const int n = rowbase + row;
            float v = acc[ct][r] + bi;
            if (n < NN) h[(size_t)n * DH + c] = v;
            hlb[w][row * 72 + c] = f2bf(v);
        }
    }
    __syncthreads();
    v4f s0 = {0.f,0.f,0.f,0.f}, s1 = {0.f,0.f,0.f,0.f};
#pragma unroll
    for (int t = 0; t < 2; ++t) {
        v8s av = *(const v8s*)&hlb[w][la * 72 + t * 32 + lb * 8];
        v8s b0 = *(const v8s*)&WcB[(size_t)(lane) * 16 + t * 8];
        v8s b1 = *(const v8s*)&WcB[(size_t)(64 + lane) * 16 + t * 8];
        s0 = MF(av, b0, s0);
        s1 = MF(av, b1, s1);
    }
#pragma unroll
    for (int r = 0; r < 4; ++r) {
        const int n = rowbase + lb * 4 + r;
        if (n < NN) {
            S[(size_t)n * 20 + la] = s0[r];
            if (la < 4) S[(size_t)n * 20 + 16 + la] = s1[r];
        }
    }
}

// ---------------- all-layer combined attention weights (+ transposed WeT) ----------------
__global__ void k_comb3(const float* __restrict__ Ws, const float* __restrict__ asrc,
                        const float* __restrict__ adst, const float* __restrict__ We_in,
                        const float* __restrict__ aedge, float* __restrict__ Wcomb,
                        float* __restrict__ WeT) {
    int layer = blockIdx.y;
    int tid = blockIdx.x * blockDim.x + threadIdx.x;
    if (tid < DH * 2 * NHD) {                      // 1280
        int k = tid / 20, j = tid % 20;
        int hh = j % NHD;
        const float* a = ((j < NHD) ? asrc : adst) + (size_t)layer * NHD * DH + hh * DH;
        const float* w = Ws + ((size_t)layer * DH + k) * (NHD * DH) + hh * DH;
        float s = 0.f;
#pragma unroll
        for (int f = 0; f < DH; ++f) s += w[f] * a[f];
        Wcomb[layer * 1280 + tid] = s;
    } else if (tid < DH * 2 * NHD + DE * NHD) {    // +160
        int t = tid - DH * 2 * NHD;
        int d = t / NHD, hh = t % NHD;
        const float* a = aedge + (size_t)layer * NHD * DH + hh * DH;
        const float* w = We_in + ((size_t)layer * DE + d) * (NHD * DH) + hh * DH;
        float s = 0.f;
#pragma unroll
        for (int f = 0; f < DH; ++f) s += w[f] * a[f];
        WeT[layer * 160 + hh * 16 + d] = s;        // [h][d] transposed
    }
}

// ---------------- BtP: B in fragment-major layout [l][ct][t][lane][8] ----------------
// element = Ws[l][k][q*64+f]*0.1, f = ct*16+(ln&15), kidx = t*32+(ln>>4)*8+e, k=kidx/10, q=kidx%10
__global__ void k_prepBP(const float* __restrict__ Ws, unsigned short* __restrict__ BtP) {
    int tid = blockIdx.x * blockDim.x + threadIdx.x;
    if (tid >= NL * 40960) return;
    int e  = tid & 7;
    int ln = (tid >> 3) & 63;
    int t  = (tid >> 9) % 20;
    int ct = (tid / 10240) & 3;
    int l  = tid / 40960;
    int f = ct * 16 + (ln & 15);
    int kidx = t * 32 + (ln >> 4) * 8 + e;
    int k = kidx / 10, q = kidx - 10 * (kidx / 10);
    float v = Ws[((size_t)l * DH + k) * 640 + q * 64 + f] * 0.1f;
    BtP[tid] = f2bf(v);
}

// ---------------- Wcomb in MFMA B-fragment layout (bf16), per layer, 2 col-tiles ----------------
__global__ void k_wcb(const float* __restrict__ Wcomb, unsigned short* __restrict__ WcB) {
    int tid = blockIdx.x * blockDim.x + threadIdx.x;
    if (tid >= NL * 2 * 64 * 16) return;
    int l = tid / 2048, r = tid % 2048;
    int tile = r / 1024, rr = r % 1024;
    int ln = rr / 16, idx = rr % 16;
    int t = idx / 8, e = idx % 8;
    int k = t * 32 + (ln >> 4) * 8 + e;
    int jc = ln & 15;
    float v = 0.f;
    if (tile == 0 || jc < 4) v = Wcomb[l * 1280 + k * 20 + tile * 16 + jc];
    WcB[tid] = f2bf(v);
}

// ---------------- alpha per (slot, head): fully parallel, a_e inline, fp16 out ----------------
__global__ void k_alpha(const float* __restrict__ S, const float* __restrict__ ea,
                        const float* __restrict__ loop, const float* __restrict__ WeT,
                        const int* __restrict__ scsr, const int* __restrict__ dcsr,
                        const int* __restrict__ eidx, __half* __restrict__ wraw) {
    int tid = blockIdx.x * blockDim.x + threadIdx.x;
    if (tid >= E2 * NHD) return;
    int s = tid / NHD, h = tid - (tid / NHD) * NHD;
    int sn = scsr[s], dn = dcsr[s], eid = eidx[s];
    const float* ar = (eid < NE) ? (ea + (size_t)eid * DE) : (loop + (size_t)(eid - NE) * DE);
    const float* wt = WeT + h * 16;
    float4 a0 = *(const float4*)(ar + 0);
    float4 a1 = *(const float4*)(ar + 4);
    float4 a2 = *(const float4*)(ar + 8);
    float4 a3 = *(const float4*)(ar + 12);
    float4 w0 = *(const float4*)(wt + 0);
    float4 w1 = *(const float4*)(wt + 4);
    float4 w2 = *(const float4*)(wt + 8);
    float4 w3 = *(const float4*)(wt + 12);
    float aev = a0.x*w0.x + a0.y*w0.y + a0.z*w0.z + a0.w*w0.w
              + a1.x*w1.x + a1.y*w1.y + a1.z*w1.z + a1.w*w1.w
              + a2.x*w2.x + a2.y*w2.y + a2.z*w2.z + a2.w*w2.w
              + a3.x*w3.x + a3.y*w3.y + a3.z*w3.z + a3.w*w3.w;
    float a = S[(size_t)sn * 20 + h] + S[(size_t)dn * 20 + 10 + h] + aev;
    a = (a > 0.f) ? a : 0.2f * a;
    wraw[tid] = (__half)a;
}

// ---------------- per-(node,head): softmax -> fixed-slot weights wfix[n][64]; tails in-place ----------------
__global__ void k_wfix(const __half* __restrict__ wraw_c, __half* __restrict__ wraw,
                       const int* __restrict__ rp, float* __restrict__ wfix) {
    int tid = blockIdx.x * blockDim.x + threadIdx.x;
    if (tid >= NN * NHD) return;
    int n = tid / NHD, h = tid - (tid / NHD) * NHD;
    int r0 = rp[n], deg = rp[n + 1] - r0;
    float m = -1e30f;
    for (int s = 0; s < deg; ++s) m = fmaxf(m, (float)wraw_c[(size_t)(r0 + s) * NHD + h]);
    float z = 0.f;
    for (int s = 0; s < deg; ++s) z += __expf((float)wraw_c[(size_t)(r0 + s) * NHD + h] - m);
    float zi = 1.f / z;
#pragma unroll
    for (int j = 0; j < 6; ++j) {
        float v = 0.f;
        if (j < deg) v = __expf((float)wraw_c[(size_t)(r0 + j) * NHD + h] - m) * zi;
        wfix[(size_t)n * 64 + j * NHD + h] = v;
    }
    for (int s = 6; s < deg; ++s) {
        float v = __expf((float)wraw_c[(size_t)(r0 + s) * NHD + h] - m) * zi;
        wraw[(size_t)(r0 + s) * NHD + h] = (__half)v;
    }
}

// ---------------- fused layer: reg-only agg -> LDS G tile -> MFMA -> epilogue -> next-S ----------------
// 256 threads = 4 waves, 16 nodes/block (grid exact 3125); wave w owns nodes w*4..w*4+3.
__global__ __launch_bounds__(256) void k_layer(
        const float* __restrict__ wfix, const __half* __restrict__ wraw,
        const int* __restrict__ snl6, const int* __restrict__ scsr,
        const float* __restrict__ hin, const unsigned short* __restrict__ BtP,
        const unsigned short* __restrict__ WcB, int do_s, float* __restrict__ Sout,
        const float* __restrict__ bias, const float* __restrict__ gam,
        const float* __restrict__ bet, const float* __restrict__ mean,
        const float* __restrict__ var, float* __restrict__ hout) {
    __shared__ __align__(16) unsigned short Gl[16 * 648];   // 20736 B

    const int tid = threadIdx.x;
    const int w = tid >> 6, lane = tid & 63;
    const int el = lane / NHD;          // slot for staging lanes (<60)
    const int blk = blockIdx.x;
    const int nb4 = blk * 16 + w * 4;

    // ---- Phase A: all addresses immediate; single-dep gathers ----
    const int meta = snl6[nb4 * 8 + (lane & 31)];   // lanes 0..31: [s0..s5,deg,r0] x4 nodes
    float wv[4];
#pragma unroll
    for (int i = 0; i < 4; ++i) wv[i] = wfix[(size_t)(nb4 + i) * 64 + lane];
    float hv[4][6];
#pragma unroll
    for (int i = 0; i < 4; ++i) {
#pragma unroll
        for (int j = 0; j < 6; ++j) {
            int sv = RLI(meta, i * 8 + j);
            hv[i][j] = hin[(size_t)sv * DH + lane];
        }
    }
#pragma unroll
    for (int i = 0; i < 4; ++i) {
        const int deg = RLI(meta, i * 8 + 6);
        const int r0  = RLI(meta, i * 8 + 7);
        float g[NHD];
#pragma unroll
        for (int q = 0; q < NHD; ++q) g[q] = 0.f;
#pragma unroll
        for (int j = 0; j < 6; ++j) {
#pragma unroll
            for (int q = 0; q < NHD; ++q)
                g[q] = fmaf(RLF(wv[i], j * 10 + q), hv[i][j], g[q]);
        }
        if (deg > 6) {
            for (int c0 = 6; c0 < deg; c0 += 6) {
                float w2 = (lane < 60 && el < deg - c0)
                           ? (float)wraw[(size_t)(r0 + c0) * NHD + lane] : 0.f;
                int s2 = (lane < 6 && c0 + lane < deg) ? scsr[r0 + c0 + lane] : 0;
                float hv2[6];
#pragma unroll
                for (int j = 0; j < 6; ++j) {
                    int sv = RLI(s2, j);
                    hv2[j] = hin[(size_t)sv * DH + lane];
                }
#pragma unroll
                for (int j = 0; j < 6; ++j)
#pragma unroll
                    for (int q = 0; q < NHD; ++q)
                        g[q] = fmaf(RLF(w2, j * 10 + q), hv2[j], g[q]);
            }
        }
        // write G row: G[li][k*10+q], lane=k -> 5 packed dwords
        const int li = w * 4 + i;
        const int base = li * 648 + lane * 10;
#pragma unroll
        for (int p = 0; p < 5; ++p) {
            unsigned u = (unsigned)f2bf(g[2 * p]) | ((unsigned)f2bf(g[2 * p + 1]) << 16);
            *(unsigned*)&Gl[base + 2 * p] = u;
        }
    }
    __syncthreads();

    // ---- Phase B: xc = G @ B, one 16x16 col-tile per wave, K=640; BtP coalesced ----
    const int la = lane & 15, lb = lane >> 4;
    v4f acc = {0.f, 0.f, 0.f, 0.f};
    const unsigned short* bp = BtP + (size_t)w * 20 * 512;
#pragma unroll 5
    for (int t = 0; t < 20; ++t) {
        v8s av = *(const v8s*)&Gl[la * 648 + t * 32 + lb * 8];
        v8s bv = *(const v8s*)&bp[t * 512 + lane * 8];
        acc = MF(av, bv, acc);
    }
    __syncthreads();      // Gl reads done; epilogue reuses Gl as bf16 h-tile

    // ---- epilogue: bias + BN + gelu + residual; stash hout tile (bf16) in LDS ----
    unsigned short* hlb = Gl;           // [16][72] bf16 (alias)
    const int f = w * 16 + la;
    const float bi = bias[f], gm = gam[f], bt_ = bet[f], mu = mean[f];
    const float iv = rsqrtf(var[f] + 1e-5f);
#pragma unroll
    for (int r = 0; r < 4; ++r) {
        const int local = lb * 4 + r;
        const int n = blk * 16 + local;
        float hvold = hin[(size_t)n * DH + f];
        float v = acc[r] + bi;
        v = (v - mu) * gm * iv + bt_;
        v = 0.5f * v * (1.0f + erff(v * 0.70710678118654752f));
        float hnew = hvold + v;
        hout[(size_t)n * DH + f] = hnew;
        hlb[local * 72 + f] = f2bf(hnew);
    }

    // ---- fused next-layer scores: S[16][20] via MFMA on 2 waves ----
    if (do_s) {
        __syncthreads();
        if (w < 2) {
            v4f sa = {0.f, 0.f, 0.f, 0.f};
#pragma unroll
            for (int t = 0; t < 2; ++t) {
                v8s av = *(const v8s*)&hlb[la * 72 + t * 32 + lb * 8];
                v8s bv = *(const v8s*)&WcB[(size_t)(w * 64 + lane) * 16 + t * 8];
                sa = MF(av, bv, sa);
            }
#pragma unroll
            for (int r = 0; r < 4; ++r) {
                const int n = blk * 16 + lb * 4 + r;
                if (w == 0) Sout[(size_t)n * 20 + la] = sa[r];
                else if (la < 4) Sout[(size_t)n * 20 + 16 + la] = sa[r];
            }
        }
    }
}

// ---------------- readout: out[g] = (segsum(h)[g] @ W_out + cnt*b_out) / max(cnt,1) ----------------
__global__ __launch_bounds__(256) void k_gout(const float* __restrict__ h,
        const float* __restrict__ W, const float* __restrict__ b,
        const int* __restrict__ grp, float* __restrict__ out) {
    __shared__ float Wl[DH * DOUTC];  // 32 KB
    __shared__ float hl[4][DH];
    __shared__ float cl[4];
    for (int i = threadIdx.x; i < DH * DOUTC; i += 256) Wl[i] = W[i];
    int w = threadIdx.x >> 6, lane = threadIdx.x & 63;
    int g = blockIdx.x * 4 + w;
    int r0 = grp[g], r1 = grp[g + 1];
    float s = 0.f;
    for (int n = r0; n < r1; ++n) s += h[(size_t)n * DH + lane];
    hl[w][lane] = s;
    if (lane == 0) cl[w] = (float)(r1 - r0);
    __syncthreads();
    for (int idx = threadIdx.x; idx < 4 * DOUTC; idx += 256) {
        int gi = idx >> 7, c = idx & 127;
        float cnt = cl[gi];
        float inv = 1.f / fmaxf(cnt, 1.f);
        float acc = cnt * b[c];
        const float* hr = hl[gi];
#pragma unroll 16
        for (int k = 0; k < DH; ++k) acc += hr[k] * Wl[k * DOUTC + c];
        out[(size_t)(blockIdx.x * 4 + gi) * DOUTC + c] = acc * inv;
    }
}

// ---------------- launcher ----------------
extern "C" void kernel_launch(void* const* d_in, const int* in_sizes, int n_in,
                              void* d_out, int out_size, void* d_ws, size_t ws_size,
                              hipStream_t stream) {
    const float* x        = (const float*)d_in[0];
    const float* edge_attr= (const float*)d_in[1];
    const float* W_emb    = (const float*)d_in[2];
    const float* b_emb    = (const float*)d_in[3];
    const float* Ws       = (const float*)d_in[4];
    const float* att_src  = (const float*)d_in[5];
    const float* att_dst  = (const float*)d_in[6];
    const float* att_edge = (const float*)d_in[7];
    const float* W_edge   = (const float*)d_in[8];
    const float* bias     = (const float*)d_in[9];
    const float* bn_gamma = (const float*)d_in[10];
    const float* bn_beta  = (const float*)d_in[11];
    const float* bn_mean  = (const float*)d_in[12];
    const float* bn_var   = (const float*)d_in[13];
    const float* W_out    = (const float*)d_in[14];
    const float* b_out    = (const float*)d_in[15];
    const int*   srcp     = (const int*)d_in[16];
    const int*   dstp     = srcp + NE;
    const int*   batch    = (const int*)d_in[17];
    float* out = (float*)d_out;

    char* wsb = (char*)d_ws;
    size_t off = 0;
    auto alloc = [&](size_t bytes) -> void* {
        void* p = (void*)(wsb + off);
        off += (bytes + 255) & ~(size_t)255;
        return p;
    };
    float*  h0    = (float*)alloc((size_t)NN * DH * 4);
    float*  h1    = (float*)alloc((size_t)NN * DH * 4);
    float*  S     = (float*)alloc((size_t)NN * 20 * 4);
    __half* wraw  = (__half*)alloc((size_t)E2 * NHD * 2);
    float*  wfix  = (float*)alloc((size_t)NN * 64 * 4);
    float*  loop  = (float*)alloc((size_t)NN * DE * 4);
    int*    cnt   = (int*)alloc((size_t)NN * 4);
    int*    rp    = (int*)alloc((size_t)(NN + 1) * 4);
    int*    cursor= (int*)alloc((size_t)NN * 4);
    int*    eidx  = (int*)alloc((size_t)E2 * 4);
    int*    scsr  = (int*)alloc((size_t)E2 * 4);
    int*    dcsr  = (int*)alloc((size_t)E2 * 4);
    int*    snl6  = (int*)alloc((size_t)NN * 8 * 4);
    int*    bsum  = (int*)alloc((size_t)SCAN_NB * 4);
    int*    grp   = (int*)alloc((size_t)(NG + 1) * 4);
    float*  WcombA= (float*)alloc((size_t)NL * DH * 20 * 4);
    float*  WeT   = (float*)alloc((size_t)NL * 160 * 4);
    unsigned short* BtP = (unsigned short*)alloc((size_t)NL * 40960 * 2);
    unsigned short* WcB = (unsigned short*)alloc((size_t)NL * 2 * 64 * 16 * 2);
    unsigned short* BH  = (unsigned short*)alloc((size_t)DH * 64 * 2);
    unsigned short* BL  = (unsigned short*)alloc((size_t)DH * 64 * 2);

    hipMemsetAsync(cnt,    0, (size_t)NN * 4, stream);
    hipMemsetAsync(cursor, 0, (size_t)NN * 4, stream);

    // preprocessing: CSR + packed metadata + self-loop attrs + graph ptrs
    k_cnt<<<(NE + 255) / 256, 256, 0, stream>>>(dstp, cnt);
    k_scan_a<<<SCAN_NB, SCAN_B, 0, stream>>>(cnt, bsum);
    k_scan_b<<<1, 64, 0, stream>>>(bsum);
    k_scan_c<<<SCAN_NB, SCAN_B, 0, stream>>>(cnt, bsum, rp);
    k_csr_fill<<<(E2 + 255) / 256, 256, 0, stream>>>(srcp, dstp, rp, cursor, eidx, scsr, dcsr);
    k_snl6<<<(NN * 8 + 255) / 256, 256, 0, stream>>>(rp, scsr, snl6);
    k_loopattr<<<(NN * DE + 255) / 256, 256, 0, stream>>>(rp, eidx, cnt, edge_attr, loop);
    k_grp<<<(NN + 255) / 256, 256, 0, stream>>>(batch, grp);

    // per-layer constants
    {
        dim3 g(6, NL);
        k_comb3<<<g, 256, 0, stream>>>(Ws, att_src, att_dst, W_edge, att_edge, WcombA, WeT);
    }
    k_prepBP<<<(NL * 40960 + 255) / 256, 256, 0, stream>>>(Ws, BtP);
    k_wcb<<<(NL * 2 * 64 * 16 + 255) / 256, 256, 0, stream>>>(WcombA, WcB);
    k_prepWemb<<<(DH * 64 + 255) / 256, 256, 0, stream>>>(W_emb, BH, BL);

    // embedding (MFMA) + fused layer-0 scores
    k_emb<<<(NN + 63) / 64, 256, 0, stream>>>(x, BH, BL, b_emb, WcB, h0, S);

    float* hb[2] = {h0, h1};
    for (int l = 0; l < NL; ++l) {
        float* hin  = hb[l & 1];
        float* hout = hb[(l + 1) & 1];
        k_alpha<<<(E2 * NHD + 255) / 256, 256, 0, stream>>>(
            S, edge_attr, loop, WeT + (size_t)l * 160, scsr, dcsr, eidx, wraw);
        k_wfix<<<(NN * NHD + 255) / 256, 256, 0, stream>>>(wraw, wraw, rp, wfix);
        k_layer<<<NN / 16, 256, 0, stream>>>(
            wfix, wraw, snl6, scsr, hin, BtP + (size_t)l * 40960,
            WcB + (size_t)(l + 1 < NL ? l + 1 : 0) * 2048,
            (l + 1 < NL) ? 1 : 0, S,
            bias + l * DH, bn_gamma + l * DH, bn_beta + l * DH,
            bn_mean + l * DH, bn_var + l * DH, hout);
    }
    float* hfin = hb[NL & 1];

    // readout
    k_gout<<<NG / 4, 256, 0, stream>>>(hfin, W_out, b_out, grp, out);
}

// Round 10
// 236.815 us; speedup vs baseline: 1.4211x; 1.0491x over previous
//
#include <hip/hip_runtime.h>
#include <hip/hip_fp16.h>
#include <math.h>

// ---------------- problem constants ----------------
constexpr int NN   = 50000;          // nodes
constexpr int NE   = 150000;         // edges
constexpr int DIN  = 48;
constexpr int DH   = 64;
constexpr int DE   = 16;
constexpr int NHD  = 10;             // heads
constexpr int NL   = 3;              // layers
constexpr int DOUTC= 128;
constexpr int NG   = 4096;           // graphs
constexpr int E2   = NE + NN;        // edges incl self loops (200000)
constexpr int SCAN_B  = 256;
constexpr int SCAN_NB = (NN + SCAN_B - 1) / SCAN_B;   // 196

typedef __bf16 v8bf __attribute__((ext_vector_type(8)));
typedef short  v8s  __attribute__((ext_vector_type(8)));
typedef float  v4f  __attribute__((ext_vector_type(4)));

__device__ inline unsigned short f2bf(float f) {
    unsigned u = __builtin_bit_cast(unsigned, f);
    unsigned r = (u + 0x7FFFu + ((u >> 16) & 1u)) >> 16;
    return (unsigned short)r;
}

__device__ inline v4f MF(v8s a, v8s b, v4f c) {
    return __builtin_amdgcn_mfma_f32_16x16x32_bf16(
        __builtin_bit_cast(v8bf, a), __builtin_bit_cast(v8bf, b), c, 0, 0, 0);
}
__device__ inline v4f MFB(v8bf a, v8s b, v4f c) {
    return __builtin_amdgcn_mfma_f32_16x16x32_bf16(
        a, __builtin_bit_cast(v8bf, b), c, 0, 0, 0);
}

// broadcast from a compile-time lane (no LDS)
#define RLI(v, l) __builtin_amdgcn_readlane((v), (l))
#define RLH2(v, l) __builtin_bit_cast(__half2, __builtin_amdgcn_readlane(__builtin_bit_cast(int, (v)), (l)))

// ---------------- preprocessing ----------------
__global__ void k_cnt(const int* __restrict__ dst, int* __restrict__ cnt) {
    int e = blockIdx.x * blockDim.x + threadIdx.x;
    if (e < NE) atomicAdd(&cnt[dst[e]], 1);
}

__global__ void k_scan_a(const int* __restrict__ cnt, int* __restrict__ bsum) {
    __shared__ int s[SCAN_B];
    int i = blockIdx.x * SCAN_B + threadIdx.x;
    s[threadIdx.x] = (i < NN) ? (cnt[i] + 1) : 0;   // +1 = self loop
    __syncthreads();
    for (int off = SCAN_B / 2; off > 0; off >>= 1) {
        if (threadIdx.x < off) s[threadIdx.x] += s[threadIdx.x + off];
        __syncthreads();
    }
    if (threadIdx.x == 0) bsum[blockIdx.x] = s[0];
}

__global__ void k_scan_b(int* __restrict__ bsum) {
    if (threadIdx.x == 0 && blockIdx.x == 0) {
        int acc = 0;
        for (int i = 0; i < SCAN_NB; ++i) { int v = bsum[i]; bsum[i] = acc; acc += v; }
    }
}

__global__ void k_scan_c(const int* __restrict__ cnt, const int* __restrict__ bsum,
                         int* __restrict__ rp) {
    __shared__ int s[SCAN_B];
    int i = blockIdx.x * SCAN_B + threadIdx.x;
    int v = (i < NN) ? (cnt[i] + 1) : 0;
    s[threadIdx.x] = v;
    __syncthreads();
    for (int off = 1; off < SCAN_B; off <<= 1) {
        int t = (threadIdx.x >= off) ? s[threadIdx.x - off] : 0;
        __syncthreads();
        s[threadIdx.x] += t;
        __syncthreads();
    }
    if (i < NN) {
        int excl = bsum[blockIdx.x] + s[threadIdx.x] - v;
        rp[i] = excl;
        if (i == NN - 1) rp[NN] = excl + v;
    }
}

__global__ void k_csr_fill(const int* __restrict__ src, const int* __restrict__ dst,
                           const int* __restrict__ rp, int* __restrict__ cursor,
                           int* __restrict__ eidx, int* __restrict__ scsr,
                           int* __restrict__ dcsr) {
    int e = blockIdx.x * blockDim.x + threadIdx.x;
    if (e >= E2) return;
    int d  = (e < NE) ? dst[e] : (e - NE);
    int sn = (e < NE) ? src[e] : d;
    int pos = atomicAdd(&cursor[d], 1);
    int s = rp[d] + pos;
    eidx[s] = e; scsr[s] = sn; dcsr[s] = d;
}

// merged: snl6 metadata + graph row ptrs + self-loop attrs
__global__ void k_misc(const int* __restrict__ rp, const int* __restrict__ scsr,
                       const int* __restrict__ eidx, const int* __restrict__ cnt,
                       const float* __restrict__ ea, const int* __restrict__ batch,
                       int* __restrict__ snl6, int* __restrict__ grp,
                       float* __restrict__ loop) {
    int tid = blockIdx.x * blockDim.x + threadIdx.x;
    if (tid < NN * 8) {
        int n = tid >> 3, j = tid & 7;
        int r0 = rp[n], deg = rp[n + 1] - r0;
        int v;
        if (j < 6)       v = (j < deg) ? scsr[r0 + j] : 0;
        else if (j == 6) v = deg;
        else             v = r0;
        snl6[tid] = v;
    } else if (tid < NN * 9) {
        int n = tid - NN * 8;
        int b = batch[n];
        int pb = (n == 0) ? -1 : batch[n - 1];
        for (int g = pb + 1; g <= b; ++g) grp[g] = n;
        if (n == NN - 1) for (int g = b + 1; g <= NG; ++g) grp[g] = NN;
    } else if (tid < NN * 25) {
        int t = tid - NN * 9;
        int n = t >> 4, d = t & 15;
        int r0 = rp[n], r1 = rp[n + 1];
        float s = 0.f;
        for (int q = r0; q < r1; ++q) {
            int eid = eidx[q];
            if (eid < NE) s += ea[(size_t)eid * DE + d];
        }
        int c = cnt[n];
        loop[t] = s * ((c > 1) ? (1.0f / (float)c) : 1.0f);
    }
}

// ---------------- merged constant prep: BtP + WcB + W_emb hi/lo ----------------
// BtP: B fragment-major [l][ct][t][lane][8]; elem = Ws[l][k][q*64+f]*0.1
// WcB: Wcomb in MFMA B-frag layout, 2 col-tiles per layer
// BH/BL: W_emb hi/lo bf16 in B-frag layout [c*64+k]
__global__ void k_prep(const float* __restrict__ Ws, const float* __restrict__ Wcomb,
                       const float* __restrict__ Wemb, unsigned short* __restrict__ BtP,
                       unsigned short* __restrict__ WcB, unsigned short* __restrict__ BH,
                       unsigned short* __restrict__ BL) {
    int tid = blockIdx.x * blockDim.x + threadIdx.x;
    if (tid < NL * 40960) {
        int e  = tid & 7;
        int ln = (tid >> 3) & 63;
        int t  = (tid >> 9) % 20;
        int ct = (tid / 10240) & 3;
        int l  = tid / 40960;
        int f = ct * 16 + (ln & 15);
        int kidx = t * 32 + (ln >> 4) * 8 + e;
        int k = kidx / 10, q = kidx - 10 * (kidx / 10);
        float v = Ws[((size_t)l * DH + k) * 640 + q * 64 + f] * 0.1f;
        BtP[tid] = f2bf(v);
    } else if (tid < NL * 40960 + NL * 2048) {
        int r0 = tid - NL * 40960;
        int l = r0 / 2048, r = r0 % 2048;
        int tile = r / 1024, rr = r % 1024;
        int ln = rr / 16, idx = rr % 16;
        int t = idx / 8, e = idx % 8;
        int k = t * 32 + (ln >> 4) * 8 + e;
        int jc = ln & 15;
        float v = 0.f;
        if (tile == 0 || jc < 4) v = Wcomb[l * 1280 + k * 20 + tile * 16 + jc];
        WcB[r0] = f2bf(v);
    } else if (tid < NL * 40960 + NL * 2048 + DH * 64) {
        int r0 = tid - NL * 40960 - NL * 2048;
        int c = r0 >> 6, k = r0 & 63;
        float v = (k < DIN) ? Wemb[(size_t)k * DH + c] : 0.f;
        __bf16 hi = (__bf16)v;
        BH[r0] = __builtin_bit_cast(unsigned short, hi);
        BL[r0] = __builtin_bit_cast(unsigned short, (__bf16)(v - (float)hi));
    }
}

// ---------------- embedding via MFMA (hi/lo split) + fused layer-0 scores ----------------
__global__ __launch_bounds__(256) void k_emb(const float* __restrict__ x,
        const unsigned short* __restrict__ BH, const unsigned short* __restrict__ BL,
        const float* __restrict__ bemb, const unsigned short* __restrict__ WcB,
        float* __restrict__ h, float* __restrict__ S) {
    __shared__ __align__(16) unsigned short hlb[4][16 * 72];
    const int tid = threadIdx.x;
    const int w = tid >> 6, lane = tid & 63;
    const int la = lane & 15, lb = lane >> 4;
    const int rowbase = blockIdx.x * 64 + w * 16;
    const int nA = rowbase + la;

    v8bf ah[2], al[2];
#pragma unroll
    for (int ks = 0; ks < 2; ++ks) {
        const int k0 = ks * 32 + lb * 8;
        float xv[8];
        if (nA < NN && k0 < DIN) {
            const float* xp = x + (size_t)nA * DIN + k0;
            float4 v0 = *(const float4*)xp;
            float4 v1 = *(const float4*)(xp + 4);
            xv[0]=v0.x; xv[1]=v0.y; xv[2]=v0.z; xv[3]=v0.w;
            xv[4]=v1.x; xv[5]=v1.y; xv[6]=v1.z; xv[7]=v1.w;
        } else {
#pragma unroll
            for (int e = 0; e < 8; ++e) xv[e] = 0.f;
        }
#pragma unroll
        for (int e = 0; e < 8; ++e) {
            __bf16 hi = (__bf16)xv[e];
            ah[ks][e] = hi;
            al[ks][e] = (__bf16)(xv[e] - (float)hi);
        }
    }
    v4f acc[4];
#pragma unroll
    for (int ct = 0; ct < 4; ++ct) acc[ct] = (v4f){0.f, 0.f, 0.f, 0.f};
#pragma unroll
    for (int ct = 0; ct < 4; ++ct) {
#pragma unroll
        for (int ks = 0; ks < 2; ++ks) {
            const int boff = (ct * 16 + la) * 64 + ks * 32 + lb * 8;
            v8s bh = *(const v8s*)&BH[boff];
            v8s bl = *(const v8s*)&BL[boff];
            acc[ct] = MFB(ah[ks], bh, acc[ct]);
            acc[ct] = MFB(al[ks], bh, acc[ct]);
            acc[ct] = MFB(ah[ks], bl, acc[ct]);
        }
    }
#pragma unroll
    for (int ct = 0; ct < 4; ++ct) {
        const int c = ct * 16 + la;
        const float bi = bemb[c];
#pragma unroll
        for (int r = 0; r < 4; ++r) {
            const int row = lb * 4 + r;
            const int n = rowbase + row;
            float v = acc[ct][r] + bi;
            if (n < NN) h[(size_t)n * DH + c] = v;
            hlb[w][row * 72 + c] = f2bf(v);
        }
    }
    __syncthreads();
    v4f s0 = {0.f,0.f,0.f,0.f}, s1 = {0.f,0.f,0.f,0.f};
#pragma unroll
    for (int t = 0; t < 2; ++t) {
        v8s av = *(const v8s*)&hlb[w][la * 72 + t * 32 + lb * 8];
        v8s b0 = *(const v8s*)&WcB[(size_t)(lane) * 16 + t * 8];
        v8s b1 = *(const v8s*)&WcB[(size_t)(64 + lane) * 16 + t * 8];
        s0 = MF(av, b0, s0);
        s1 = MF(av, b1, s1);
    }
#pragma unroll
    for (int r = 0; r < 4; ++r) {
        const int n = rowbase + lb * 4 + r;
        if (n < NN) {
            S[(size_t)n * 20 + la] = s0[r];
            if (la < 4) S[(size_t)n * 20 + 16 + la] = s1[r];
        }
    }
}

// ---------------- all-layer combined attention weights (+ transposed WeT) ----------------
__global__ void k_comb3(const float* __restrict__ Ws, const float* __restrict__ asrc,
                        const float* __restrict__ adst, const float* __restrict__ We_in,
                        const float* __restrict__ aedge, float* __restrict__ Wcomb,
                        float* __restrict__ WeT) {
    int layer = blockIdx.y;
    int tid = blockIdx.x * blockDim.x + threadIdx.x;
    if (tid < DH * 2 * NHD) {                      // 1280
        int k = tid / 20, j = tid % 20;
        int hh = j % NHD;
        const float* a = ((j < NHD) ? asrc : adst) + (size_t)layer * NHD * DH + hh * DH;
        const float* w = Ws + ((size_t)layer * DH + k) * (NHD * DH) + hh * DH;
        float s = 0.f;
#pragma unroll
        for (int f = 0; f < DH; ++f) s += w[f] * a[f];
        Wcomb[layer * 1280 + tid] = s;
    } else if (tid < DH * 2 * NHD + DE * NHD) {    // +160
        int t = tid - DH * 2 * NHD;
        int d = t / NHD, hh = t % NHD;
        const float* a = aedge + (size_t)layer * NHD * DH + hh * DH;
        const float* w = We_in + ((size_t)layer * DE + d) * (NHD * DH) + hh * DH;
        float s = 0.f;
#pragma unroll
        for (int f = 0; f < DH; ++f) s += w[f] * a[f];
        WeT[layer * 160 + hh * 16 + d] = s;        // [h][d] transposed
    }
}

// ---------------- alpha per (slot, head): fully parallel, a_e inline, fp16 out ----------------
__global__ void k_alpha(const float* __restrict__ S, const float* __restrict__ ea,
                        const float* __restrict__ loop, const float* __restrict__ WeT,
                        const int* __restrict__ scsr, const int* __restrict__ dcsr,
                        const int* __restrict__ eidx, __half* __restrict__ wraw) {
    int tid = blockIdx.x * blockDim.x + threadIdx.x;
    if (tid >= E2 * NHD) return;
    int s = tid / NHD, h = tid - (tid / NHD) * NHD;
    int sn = scsr[s], dn = dcsr[s], eid = eidx[s];
    const float* ar = (eid < NE) ? (ea + (size_t)eid * DE) : (loop + (size_t)(eid - NE) * DE);
    const float* wt = WeT + h * 16;
    float4 a0 = *(const float4*)(ar + 0);
    float4 a1 = *(const float4*)(ar + 4);
    float4 a2 = *(const float4*)(ar + 8);
    float4 a3 = *(const float4*)(ar + 12);
    float4 w0 = *(const float4*)(wt + 0);
    float4 w1 = *(const float4*)(wt + 4);
    float4 w2 = *(const float4*)(wt + 8);
    float4 w3 = *(const float4*)(wt + 12);
    float aev = a0.x*w0.x + a0.y*w0.y + a0.z*w0.z + a0.w*w0.w
              + a1.x*w1.x + a1.y*w1.y + a1.z*w1.z + a1.w*w1.w
              + a2.x*w2.x + a2.y*w2.y + a2.z*w2.z + a2.w*w2.w
              + a3.x*w3.x + a3.y*w3.y + a3.z*w3.z + a3.w*w3.w;
    float a = S[(size_t)sn * 20 + h] + S[(size_t)dn * 20 + 10 + h] + aev;
    a = (a > 0.f) ? a : 0.2f * a;
    wraw[tid] = (__half)a;
}

// ---------------- per-(node,head): softmax -> packed half weights wfixh[n][64]; tails in-place ----------------
// wfixh half index n*64 + j*10 + h  (heads 2p,2p+1 adjacent -> u32 pair index j*5+p)
__global__ void k_wfix(const __half* __restrict__ wraw_c, __half* __restrict__ wraw,
                       const int* __restrict__ rp, __half* __restrict__ wfixh) {
    int tid = blockIdx.x * blockDim.x + threadIdx.x;
    if (tid >= NN * NHD) return;
    int n = tid / NHD, h = tid - (tid / NHD) * NHD;
    int r0 = rp[n], deg = rp[n + 1] - r0;
    float m = -1e30f;
    for (int s = 0; s < deg; ++s) m = fmaxf(m, (float)wraw_c[(size_t)(r0 + s) * NHD + h]);
    float z = 0.f;
    for (int s = 0; s < deg; ++s) z += __expf((float)wraw_c[(size_t)(r0 + s) * NHD + h] - m);
    float zi = 1.f / z;
#pragma unroll
    for (int j = 0; j < 6; ++j) {
        float v = 0.f;
        if (j < deg) v = __expf((float)wraw_c[(size_t)(r0 + j) * NHD + h] - m) * zi;
        wfixh[(size_t)n * 64 + j * 10 + h] = (__half)v;
    }
    if (h < 4) wfixh[(size_t)n * 64 + 60 + h] = (__half)0.f;
    for (int s = 6; s < deg; ++s) {
        float v = __expf((float)wraw_c[(size_t)(r0 + s) * NHD + h] - m) * zi;
        wraw[(size_t)(r0 + s) * NHD + h] = (__half)v;
    }
}

// ---------------- fused layer: pk-f16 agg -> LDS G tile -> MFMA -> epilogue -> next-S ----------------
// 256 threads = 4 waves, 16 nodes/block (grid exact 3125); wave w owns nodes w*4..w*4+3.
__global__ __launch_bounds__(256) void k_layer(
        const __half* __restrict__ wfixh, const __half* __restrict__ wraw,
        const int* __restrict__ snl6, const int* __restrict__ scsr,
        const float* __restrict__ hin, const unsigned short* __restrict__ BtP,
        const unsigned short* __restrict__ WcB, int do_s, float* __restrict__ Sout,
        const float* __restrict__ bias, const float* __restrict__ gam,
        const float* __restrict__ bet, const float* __restrict__ mean,
        const float* __restrict__ var, float* __restrict__ hout) {
    __shared__ __align__(16) unsigned short Gl[16 * 648];   // 20736 B

    const int tid = threadIdx.x;
    const int w = tid >> 6, lane = tid & 63;
    const int blk = blockIdx.x;
    const int nb4 = blk * 16 + w * 4;
    const unsigned* wfixu = (const unsigned*)wfixh;
    const unsigned* wrawu = (const unsigned*)wraw;

    // ---- Phase A: immediate loads -> readlane broadcasts -> packed-f16 FMA ----
    const int meta = snl6[nb4 * 8 + (lane & 31)];   // lanes 0..31: [s0..s5,deg,r0] x4 nodes
    int wfu[4];
#pragma unroll
    for (int i = 0; i < 4; ++i)
        wfu[i] = (int)wfixu[(size_t)(nb4 + i) * 32 + (lane & 31)];
    float hv[4][6];
#pragma unroll
    for (int i = 0; i < 4; ++i) {
#pragma unroll
        for (int j = 0; j < 6; ++j) {
            int sv = RLI(meta, i * 8 + j);
            hv[i][j] = hin[(size_t)sv * DH + lane];
        }
    }
#pragma unroll
    for (int i = 0; i < 4; ++i) {
        const int deg = RLI(meta, i * 8 + 6);
        const int r0  = RLI(meta, i * 8 + 7);
        __half2 g[5];
#pragma unroll
        for (int p = 0; p < 5; ++p) g[p] = __half2{(__half)0.f, (__half)0.f};
#pragma unroll
        for (int j = 0; j < 6; ++j) {
            __half2 hvd = __float2half2_rn(hv[i][j]);
#pragma unroll
            for (int p = 0; p < 5; ++p)
                g[p] = __hfma2(RLH2(wfu[i], j * 5 + p), hvd, g[p]);
        }
        if (deg > 6) {
            for (int c0 = 6; c0 < deg; c0 += 6) {
                const int rem = deg - c0;
                int w2 = (lane < 30 && (lane / 5) < rem)
                         ? (int)wrawu[(size_t)(r0 + c0) * 5 + lane] : 0;
                int s2 = (lane < 6 && c0 + lane < deg) ? scsr[r0 + c0 + lane] : 0;
                float hv2[6];
#pragma unroll
                for (int j = 0; j < 6; ++j) {
                    int sv = RLI(s2, j);
                    hv2[j] = hin[(size_t)sv * DH + lane];
                }
#pragma unroll
                for (int j = 0; j < 6; ++j) {
                    __half2 hvd = __float2half2_rn(hv2[j]);
#pragma unroll
                    for (int p = 0; p < 5; ++p)
                        g[p] = __hfma2(RLH2(w2, j * 5 + p), hvd, g[p]);
                }
            }
        }
        // write G row: G[li][k*10+q], lane=k -> 5 packed dwords
        const int li = w * 4 + i;
        const int base = li * 648 + lane * 10;
#pragma unroll
        for (int p = 0; p < 5; ++p) {
            float f0 = __low2float(g[p]), f1 = __high2float(g[p]);
            unsigned u = (unsigned)f2bf(f0) | ((unsigned)f2bf(f1) << 16);
            *(unsigned*)&Gl[base + 2 * p] = u;
        }
    }
    __syncthreads();

    // ---- Phase B: xc = G @ B, one 16x16 col-tile per wave, K=640; BtP coalesced ----
    const int la = lane & 15, lb = lane >> 4;
    v4f acc = {0.f, 0.f, 0.f, 0.f};
    const unsigned short* bp = BtP + (size_t)w * 20 * 512;
#pragma unroll 5
    for (int t = 0; t < 20; ++t) {
        v8s av = *(const v8s*)&Gl[la * 648 + t * 32 + lb * 8];
        v8s bv = *(const v8s*)&bp[t * 512 + lane * 8];
        acc = MF(av, bv, acc);
    }
    __syncthreads();      // Gl reads done; epilogue reuses Gl as bf16 h-tile

    // ---- epilogue: bias + BN + gelu + residual; stash hout tile (bf16) in LDS ----
    unsigned short* hlb = Gl;           // [16][72] bf16 (alias)
    const int f = w * 16 + la;
    const float bi = bias[f], gm = gam[f], bt_ = bet[f], mu = mean[f];
    const float iv = rsqrtf(var[f] + 1e-5f);
#pragma unroll
    for (int r = 0; r < 4; ++r) {
        const int local = lb * 4 + r;
        const int n = blk * 16 + local;
        float hvold = hin[(size_t)n * DH + f];
        float v = acc[r] + bi;
        v = (v - mu) * gm * iv + bt_;
        v = 0.5f * v * (1.0f + erff(v * 0.70710678118654752f));
        float hnew = hvold + v;
        hout[(size_t)n * DH + f] = hnew;
        hlb[local * 72 + f] = f2bf(hnew);
    }

    // ---- fused next-layer scores: S[16][20] via MFMA on 2 waves ----
    if (do_s) {
        __syncthreads();
        if (w < 2) {
            v4f sa = {0.f, 0.f, 0.f, 0.f};
#pragma unroll
            for (int t = 0; t < 2; ++t) {
                v8s av = *(const v8s*)&hlb[la * 72 + t * 32 + lb * 8];
                v8s bv = *(const v8s*)&WcB[(size_t)(w * 64 + lane) * 16 + t * 8];
                sa = MF(av, bv, sa);
            }
#pragma unroll
            for (int r = 0; r < 4; ++r) {
                const int n = blk * 16 + lb * 4 + r;
                if (w == 0) Sout[(size_t)n * 20 + la] = sa[r];
                else if (la < 4) Sout[(size_t)n * 20 + 16 + la] = sa[r];
            }
        }
    }
}

// ---------------- readout: out[g] = (segsum(h)[g] @ W_out + cnt*b_out) / max(cnt,1) ----------------
__global__ __launch_bounds__(256) void k_gout(const float* __restrict__ h,
        const float* __restrict__ W, const float* __restrict__ b,
        const int* __restrict__ grp, float* __restrict__ out) {
    __shared__ float Wl[DH * DOUTC];  // 32 KB
    __shared__ float hl[4][DH];
    __shared__ float cl[4];
    for (int i = threadIdx.x; i < DH * DOUTC; i += 256) Wl[i] = W[i];
    int w = threadIdx.x >> 6, lane = threadIdx.x & 63;
    int g = blockIdx.x * 4 + w;
    int r0 = grp[g], r1 = grp[g + 1];
    float s = 0.f;
    for (int n = r0; n < r1; ++n) s += h[(size_t)n * DH + lane];
    hl[w][lane] = s;
    if (lane == 0) cl[w] = (float)(r1 - r0);
    __syncthreads();
    for (int idx = threadIdx.x; idx < 4 * DOUTC; idx += 256) {
        int gi = idx >> 7, c = idx & 127;
        float cnt = cl[gi];
        float inv = 1.f / fmaxf(cnt, 1.f);
        float acc = cnt * b[c];
        const float* hr = hl[gi];
#pragma unroll 16
        for (int k = 0; k < DH; ++k) acc += hr[k] * Wl[k * DOUTC + c];
        out[(size_t)(blockIdx.x * 4 + gi) * DOUTC + c] = acc * inv;
    }
}

// ---------------- launcher ----------------
extern "C" void kernel_launch(void* const* d_in, const int* in_sizes, int n_in,
                              void* d_out, int out_size, void* d_ws, size_t ws_size,
                              hipStream_t stream) {
    const float* x        = (const float*)d_in[0];
    const float* edge_attr= (const float*)d_in[1];
    const float* W_emb    = (const float*)d_in[2];
    const float* b_emb    = (const float*)d_in[3];
    const float* Ws       = (const float*)d_in[4];
    const float* att_src  = (const float*)d_in[5];
    const float* att_dst  = (const float*)d_in[6];
    const float* att_edge = (const float*)d_in[7];
    const float* W_edge   = (const float*)d_in[8];
    const float* bias     = (const float*)d_in[9];
    const float* bn_gamma = (const float*)d_in[10];
    const float* bn_beta  = (const float*)d_in[11];
    const float* bn_mean  = (const float*)d_in[12];
    const float* bn_var   = (const float*)d_in[13];
    const float* W_out    = (const float*)d_in[14];
    const float* b_out    = (const float*)d_in[15];
    const int*   srcp     = (const int*)d_in[16];
    const int*   dstp     = srcp + NE;
    const int*   batch    = (const int*)d_in[17];
    float* out = (float*)d_out;

    char* wsb = (char*)d_ws;
    size_t off = 0;
    auto alloc = [&](size_t bytes) -> void* {
        void* p = (void*)(wsb + off);
        off += (bytes + 255) & ~(size_t)255;
        return p;
    };
    float*  h0    = (float*)alloc((size_t)NN * DH * 4);
    float*  h1    = (float*)alloc((size_t)NN * DH * 4);
    float*  S     = (float*)alloc((size_t)NN * 20 * 4);
    __half* wraw  = (__half*)alloc((size_t)E2 * NHD * 2);
    __half* wfixh = (__half*)alloc((size_t)NN * 64 * 2);
    float*  loop  = (float*)alloc((size_t)NN * DE * 4);
    int*    cnt   = (int*)alloc((size_t)NN * 4);
    int*    rp    = (int*)alloc((size_t)(NN + 1) * 4);
    int*    cursor= (int*)alloc((size_t)NN * 4);
    int*    eidx  = (int*)alloc((size_t)E2 * 4);
    int*    scsr  = (int*)alloc((size_t)E2 * 4);
    int*    dcsr  = (int*)alloc((size_t)E2 * 4);
    int*    snl6  = (int*)alloc((size_t)NN * 8 * 4);
    int*    bsum  = (int*)alloc((size_t)SCAN_NB * 4);
    int*    grp   = (int*)alloc((size_t)(NG + 1) * 4);
    float*  WcombA= (float*)alloc((size_t)NL * DH * 20 * 4);
    float*  WeT   = (float*)alloc((size_t)NL * 160 * 4);
    unsigned short* BtP = (unsigned short*)alloc((size_t)NL * 40960 * 2);
    unsigned short* WcB = (unsigned short*)alloc((size_t)NL * 2 * 64 * 16 * 2);
    unsigned short* BH  = (unsigned short*)alloc((size_t)DH * 64 * 2);
    unsigned short* BL  = (unsigned short*)alloc((size_t)DH * 64 * 2);

    hipMemsetAsync(cnt,    0, (size_t)NN * 4, stream);
    hipMemsetAsync(cursor, 0, (size_t)NN * 4, stream);

    // preprocessing: CSR + merged metadata/self-loop/graph-ptr pass
    k_cnt<<<(NE + 255) / 256, 256, 0, stream>>>(dstp, cnt);
    k_scan_a<<<SCAN_NB, SCAN_B, 0, stream>>>(cnt, bsum);
    k_scan_b<<<1, 64, 0, stream>>>(bsum);
    k_scan_c<<<SCAN_NB, SCAN_B, 0, stream>>>(cnt, bsum, rp);
    k_csr_fill<<<(E2 + 255) / 256, 256, 0, stream>>>(srcp, dstp, rp, cursor, eidx, scsr, dcsr);
    k_misc<<<(NN * 25 + 255) / 256, 256, 0, stream>>>(rp, scsr, eidx, cnt, edge_attr,
                                                      batch, snl6, grp, loop);

    // per-layer constants
    {
        dim3 g(6, NL);
        k_comb3<<<g, 256, 0, stream>>>(Ws, att_src, att_dst, W_edge, att_edge, WcombA, WeT);
    }
    k_prep<<<(NL * 40960 + NL * 2048 + DH * 64 + 255) / 256, 256, 0, stream>>>(
        Ws, WcombA, W_emb, BtP, WcB, BH, BL);

    // embedding (MFMA) + fused layer-0 scores
    k_emb<<<(NN + 63) / 64, 256, 0, stream>>>(x, BH, BL, b_emb, WcB, h0, S);

    float* hb[2] = {h0, h1};
    for (int l = 0; l < NL; ++l) {
        float* hin  = hb[l & 1];
        float* hout = hb[(l + 1) & 1];
        k_alpha<<<(E2 * NHD + 255) / 256, 256, 0, stream>>>(
            S, edge_attr, loop, WeT + (size_t)l * 160, scsr, dcsr, eidx, wraw);
        k_wfix<<<(NN * NHD + 255) / 256, 256, 0, stream>>>(wraw, wraw, rp, wfixh);
        k_layer<<<NN / 16, 256, 0, stream>>>(
            wfixh, wraw, snl6, scsr, hin, BtP + (size_t)l * 40960,
            WcB + (size_t)(l + 1 < NL ? l + 1 : 0) * 2048,
            (l + 1 < NL) ? 1 : 0, S,
            bias + l * DH, bn_gamma + l * DH, bn_beta + l * DH,
            bn_mean + l * DH, bn_var + l * DH, hout);
    }
    float* hfin = hb[NL & 1];

    // readout
    k_gout<<<NG / 4, 256, 0, stream>>>(hfin, W_out, b_out, grp, out);
}